// Round 5
// baseline (691.931 us; speedup 1.0000x reference)
//
#include <hip/hip_runtime.h>
#include <hip/hip_fp16.h>

#define TT 512
#define HH 128

typedef _Float16 half2_t __attribute__((ext_vector_type(2)));
typedef _Float16 half4_t __attribute__((ext_vector_type(4)));
typedef _Float16 half8_t __attribute__((ext_vector_type(8)));
typedef float    float4_t __attribute__((ext_vector_type(4)));

__device__ __forceinline__ half2_t h2(float v) {
    half2_t r; r[0] = (_Float16)v; r[1] = (_Float16)v; return r;
}
__device__ __forceinline__ half2_t pkrtz(float a, float b) {
    return __builtin_bit_cast(half2_t, __builtin_amdgcn_cvt_pkrtz(a, b));
}

// ---- packed-f16 polynomial activations (no transcendentals) ----
#define TC1 0.994940f
#define TC3 -0.290799f
#define TC5 0.065507f
#define TC7 -0.0062464f
#define SC1 0.2487350f
#define SC3 -0.0181749f
#define SC5 0.00102355f
#define SC7 -0.0000244141f

__device__ __forceinline__ half2_t tanh_pk(half2_t x) {
    half2_t m = __builtin_elementwise_min(__builtin_elementwise_max(x, h2(-2.0f)), h2(2.0f));
    half2_t t = m * m;
    half2_t p = h2(TC7) * t + h2(TC5);
    p = p * t + h2(TC3);
    p = p * t + h2(TC1);
    return m * p;
}
__device__ __forceinline__ half2_t sigma_pk(half2_t x) {
    half2_t m = __builtin_elementwise_min(__builtin_elementwise_max(x, h2(-4.0f)), h2(4.0f));
    half2_t t = m * m;
    half2_t p = h2(SC7) * t + h2(SC5);
    p = p * t + h2(SC3);
    p = p * t + h2(SC1);
    return m * p + h2(0.5f);
}

// LDS-only barrier: waits lgkmcnt(0), leaves global loads in flight.
__device__ __forceinline__ void wg_barrier_lds() {
#if __has_builtin(__builtin_amdgcn_s_waitcnt)
    __builtin_amdgcn_s_waitcnt(0xC07F);   // lgkmcnt(0), vmcnt=max, expcnt=max
#else
    asm volatile("s_waitcnt lgkmcnt(0)" ::: "memory");
#endif
    __builtin_amdgcn_s_barrier();
}

// ---- kernel 0: one-time emb f32 -> f16 conversion (25.6 MB out, ~12us)
__global__ __launch_bounds__(256) void emb_cvt_kernel(
    const float* __restrict__ emb, _Float16* __restrict__ emb16)
{
    size_t i = ((size_t)blockIdx.x * 256 + threadIdx.x) * 8;
    const float4* s = (const float4*)(emb + i);
    float4 a = s[0], b = s[1];
    half2_t p0 = pkrtz(a.x, a.y), p1 = pkrtz(a.z, a.w);
    half2_t p2 = pkrtz(b.x, b.y), p3 = pkrtz(b.z, b.w);
    half8_t h;
    h[0]=p0[0]; h[1]=p0[1]; h[2]=p1[0]; h[3]=p1[1];
    h[4]=p2[0]; h[5]=p2[1]; h[6]=p3[0]; h[7]=p3[1];
    *(half8_t*)(emb16 + i) = h;
}

// ---- kernel 1: fully fused BiLSTM recurrence (r16).
// r13 retry minus the poison: the xp projection's B-fragments (emb rows in
// MFMA B layout) are loaded DIRECTLY from a pre-converted f16 emb table in
// global (L3-resident), not staged through LDS. Per step, per wave:
//   gates(t)  = MFMA(awhh, h(t-1), C = xp(t))     [xp(t) built last step, f32]
//   xp(t+1)   = MFMA(awih, E(t+1), C = bias)      [fills idle matrix pipe,
//                                                  overlaps activation VALU]
//   prefetch  E(t+2) frags (global, 2-step cover) + id(t+3) (1-step cover)
// LDS traffic identical to r15 (4 bh reads + 1 h write); hsm fragment-linear.
// Deletes the 134MB xp intermediate and the separate xp_gemm kernel (~148us).
__global__ __attribute__((amdgpu_flat_work_group_size(512, 512), amdgpu_waves_per_eu(2, 2)))
void bilstm_fused_kernel(
    const int* __restrict__ x, const _Float16* __restrict__ emb16,
    const float* __restrict__ Wih_f, const float* __restrict__ bih_f, const float* __restrict__ bhh_f,
    const float* __restrict__ Wih_b, const float* __restrict__ bih_b, const float* __restrict__ bhh_b,
    const float* __restrict__ Whh_f, const float* __restrict__ Whh_b,
    float* __restrict__ pooled)
{
    const int wg  = blockIdx.x;        // 0..15 dirbg
    const int dir = wg >> 3, bg = wg & 7;
    const float* Wih = dir ? Wih_b : Wih_f;
    const float* bih = dir ? bih_b : bih_f;
    const float* bhh = dir ? bhh_b : bhh_f;
    const float* Whh = dir ? Whh_b : Whh_f;

    const int tid = threadIdx.x;
    const int w = tid >> 6, lane = tid & 63, lq = lane >> 4, lm = lane & 15;

    __shared__ _Float16 hsm[2][2048];   // [buf][kk*512 + lane*8 + j] fragment-linear

    // ---- weight fragments + fused bias (r13-proven layout) ----
    half8_t awih[4][4], awhh[4][4];
    #pragma unroll
    for (int T = 0; T < 4; ++T) {
        #pragma unroll
        for (int kk = 0; kk < 4; ++kk) {
            const float4* s1 = (const float4*)(Wih + (size_t)(T * 128 + w * 16 + lm) * 128 + kk * 32 + lq * 8);
            float4 v0 = s1[0], v1 = s1[1];
            half8_t h;
            half2_t a = pkrtz(v0.x, v0.y), b = pkrtz(v0.z, v0.w);
            half2_t c = pkrtz(v1.x, v1.y), d = pkrtz(v1.z, v1.w);
            h[0]=a[0]; h[1]=a[1]; h[2]=b[0]; h[3]=b[1];
            h[4]=c[0]; h[5]=c[1]; h[6]=d[0]; h[7]=d[1];
            awih[T][kk] = h;
            const float4* s2 = (const float4*)(Whh + (size_t)(T * 128 + w * 16 + lm) * 128 + kk * 32 + lq * 8);
            float4 u0 = s2[0], u1 = s2[1];
            half8_t g;
            half2_t e = pkrtz(u0.x, u0.y), f = pkrtz(u0.z, u0.w);
            half2_t gg = pkrtz(u1.x, u1.y), hh = pkrtz(u1.z, u1.w);
            g[0]=e[0]; g[1]=e[1]; g[2]=f[0]; g[3]=f[1];
            g[4]=gg[0]; g[5]=gg[1]; g[6]=hh[0]; g[7]=hh[1];
            awhh[T][kk] = g;
        }
    }
    float4_t biasv[4];
    #pragma unroll
    for (int T = 0; T < 4; ++T) {
        int g = T * 128 + w * 16 + lq * 4;
        float4 b1 = *(const float4*)(bih + g);
        float4 b2 = *(const float4*)(bhh + g);
        biasv[T] = (float4_t){b1.x + b2.x, b1.y + b2.y, b1.z + b2.z, b1.w + b2.w};
    }

    for (int k = tid; k < 2 * 2048; k += 512)
        ((_Float16*)hsm)[k] = (_Float16)0.0f;

    // r15 fragment-linear bases (step-invariant)
    const int rbase = lane * 8;
    const int wbase = (w >> 1) * 512 + ((w & 1) * 2 + (lq >> 1)) * 128 + lm * 8 + (lq & 1) * 4;

    // per-lane token-id row (chain = bg*16 + lm; same for all lq)
    const int* xrow = x + (size_t)(bg * 16 + lm) * TT;
    #define MPT(k_) (dir ? (TT - 1 - ((k_) < TT ? (k_) : (TT - 1))) : ((k_) < TT ? (k_) : (TT - 1)))

    // ---- prologue: xp(0) in regs, E(1) staged, id(2) staged ----
    half8_t EqA[4], EqB[4];
    float4_t xpA[4], xpB[4];
    int idA, idB;
    {
        int id0 = xrow[MPT(0)];
        int id1 = xrow[MPT(1)];
        idA = xrow[MPT(2)];
        const _Float16* e0 = emb16 + (size_t)id0 * 128 + lq * 8;
        const _Float16* e1 = emb16 + (size_t)id1 * 128 + lq * 8;
        half8_t Et[4];
        #pragma unroll
        for (int kk = 0; kk < 4; ++kk) Et[kk]  = *(const half8_t*)(e0 + kk * 32);
        #pragma unroll
        for (int kk = 0; kk < 4; ++kk) EqB[kk] = *(const half8_t*)(e1 + kk * 32);
        #pragma unroll
        for (int T = 0; T < 4; ++T) xpA[T] = biasv[T];
        #pragma unroll
        for (int kk = 0; kk < 4; ++kk)
            #pragma unroll
            for (int T = 0; T < 4; ++T)
                xpA[T] = __builtin_amdgcn_mfma_f32_16x16x32_f16(awih[T][kk], Et[kk], xpA[T], 0, 0, 0);
    }
    __syncthreads();   // hsm zeros visible

    half2_t c01 = h2(0.0f), c23 = h2(0.0f);
    half2_t hm01 = h2(-60000.0f), hm23 = h2(-60000.0f);

    // One step. XPIN=xp(t) (C for rec-MFMA), XPOUT<-xp(t+1) from EQC=E(t+1);
    // EQL<-E(t+2) using IDC=id(t+2); IDL<-id(t+3). All names static (rule #20).
    #define FSTEP(T_, XPIN, XPOUT, EQC, EQL, IDC, IDL) do {                          \
        const int t_ = (T_);                                                         \
        IDL = xrow[MPT(t_ + 3)];                                                     \
        {                                                                            \
            const _Float16* ep = emb16 + (size_t)IDC * 128 + lq * 8;                 \
            EQL[0] = *(const half8_t*)(ep);                                          \
            EQL[1] = *(const half8_t*)(ep + 32);                                     \
            EQL[2] = *(const half8_t*)(ep + 64);                                     \
            EQL[3] = *(const half8_t*)(ep + 96);                                     \
        }                                                                            \
        const _Float16* hb = &hsm[t_ & 1][rbase];                                    \
        half8_t bh0 = *(const half8_t*)(hb);                                         \
        half8_t bh1 = *(const half8_t*)(hb + 512);                                   \
        half8_t bh2 = *(const half8_t*)(hb + 1024);                                  \
        half8_t bh3 = *(const half8_t*)(hb + 1536);                                  \
        float4_t acc[4];                                                             \
        _Pragma("unroll")                                                            \
        for (int T = 0; T < 4; ++T)                                                  \
            acc[T] = __builtin_amdgcn_mfma_f32_16x16x32_f16(awhh[T][0], bh0, XPIN[T], 0, 0, 0); \
        _Pragma("unroll")                                                            \
        for (int T = 0; T < 4; ++T)                                                  \
            acc[T] = __builtin_amdgcn_mfma_f32_16x16x32_f16(awhh[T][1], bh1, acc[T], 0, 0, 0);  \
        _Pragma("unroll")                                                            \
        for (int T = 0; T < 4; ++T)                                                  \
            acc[T] = __builtin_amdgcn_mfma_f32_16x16x32_f16(awhh[T][2], bh2, acc[T], 0, 0, 0);  \
        _Pragma("unroll")                                                            \
        for (int T = 0; T < 4; ++T)                                                  \
            acc[T] = __builtin_amdgcn_mfma_f32_16x16x32_f16(awhh[T][3], bh3, acc[T], 0, 0, 0);  \
        _Pragma("unroll")                                                            \
        for (int T = 0; T < 4; ++T)                                                  \
            XPOUT[T] = __builtin_amdgcn_mfma_f32_16x16x32_f16(awih[T][0], EQC[0], biasv[T], 0, 0, 0); \
        _Pragma("unroll")                                                            \
        for (int kk = 1; kk < 4; ++kk)                                               \
            _Pragma("unroll")                                                        \
            for (int T = 0; T < 4; ++T)                                              \
                XPOUT[T] = __builtin_amdgcn_mfma_f32_16x16x32_f16(awih[T][kk], EQC[kk], XPOUT[T], 0, 0, 0); \
        half2_t i01 = sigma_pk(pkrtz(acc[0][0], acc[0][1]));                         \
        half2_t i23 = sigma_pk(pkrtz(acc[0][2], acc[0][3]));                         \
        half2_t f01 = sigma_pk(pkrtz(acc[1][0], acc[1][1]));                         \
        half2_t f23 = sigma_pk(pkrtz(acc[1][2], acc[1][3]));                         \
        half2_t g01 = tanh_pk(pkrtz(acc[2][0], acc[2][1]));                          \
        half2_t g23 = tanh_pk(pkrtz(acc[2][2], acc[2][3]));                          \
        half2_t o01 = sigma_pk(pkrtz(acc[3][0], acc[3][1]));                         \
        half2_t o23 = sigma_pk(pkrtz(acc[3][2], acc[3][3]));                         \
        c01 = f01 * c01 + i01 * g01;                                                 \
        c23 = f23 * c23 + i23 * g23;                                                 \
        half2_t h01 = o01 * tanh_pk(c01);                                            \
        half2_t h23 = o23 * tanh_pk(c23);                                            \
        hm01 = __builtin_elementwise_max(hm01, h01);                                 \
        hm23 = __builtin_elementwise_max(hm23, h23);                                 \
        half4_t hv4;                                                                 \
        hv4[0] = h01[0]; hv4[1] = h01[1]; hv4[2] = h23[0]; hv4[3] = h23[1];          \
        *(half4_t*)&hsm[1 - (t_ & 1)][wbase] = hv4;                                  \
        wg_barrier_lds();                                                            \
    } while (0)

    #pragma unroll 1
    for (int t = 0; t < TT; t += 2) {
        FSTEP(t,     xpA, xpB, EqB, EqA, idA, idB);
        FSTEP(t + 1, xpB, xpA, EqA, EqB, idB, idA);
    }
    #undef FSTEP
    #undef MPT

    float4 o;
    o.x = (float)hm01[0]; o.y = (float)hm01[1];
    o.z = (float)hm23[0]; o.w = (float)hm23[1];
    *(float4*)&pooled[(size_t)(bg * 16 + lm) * 256 + dir * HH + w * 16 + lq * 4] = o;
}

// ---- kernel 3: pooled (128,256) -> relu(W1·+b1) -> sigmoid(W2·+b2) -> (128,1)
__global__ __launch_bounds__(64) void mlp_kernel(
    const float* __restrict__ pooled, const float* __restrict__ W1,
    const float* __restrict__ b1, const float* __restrict__ W2,
    const float* __restrict__ b2, float* __restrict__ out)
{
    const int b = blockIdx.x;
    const int j = threadIdx.x;
    const float4* p = (const float4*)(pooled + (size_t)b * 256);
    const float4* wv = (const float4*)(W1 + (size_t)j * 256);
    float s = 0.0f;
    #pragma unroll
    for (int q = 0; q < 64; ++q) {
        float4 pv = p[q];
        float4 ww = wv[q];
        s += pv.x * ww.x + pv.y * ww.y + pv.z * ww.z + pv.w * ww.w;
    }
    s += b1[j];
    s = fmaxf(s, 0.0f);
    float v = W2[j] * s;
    #pragma unroll
    for (int off = 32; off; off >>= 1) v += __shfl_down(v, off);
    if (j == 0) out[b] = 1.0f / (1.0f + __expf(-(v + b2[0])));
}

extern "C" void kernel_launch(void* const* d_in, const int* in_sizes, int n_in,
                              void* d_out, int out_size, void* d_ws, size_t ws_size,
                              hipStream_t stream) {
    const int*   x     = (const int*)d_in[0];
    const float* emb   = (const float*)d_in[1];
    const float* Wih_f = (const float*)d_in[2];
    const float* Whh_f = (const float*)d_in[3];
    const float* bih_f = (const float*)d_in[4];
    const float* bhh_f = (const float*)d_in[5];
    const float* Wih_b = (const float*)d_in[6];
    const float* Whh_b = (const float*)d_in[7];
    const float* bih_b = (const float*)d_in[8];
    const float* bhh_b = (const float*)d_in[9];
    const float* W1    = (const float*)d_in[10];
    const float* b1    = (const float*)d_in[11];
    const float* W2    = (const float*)d_in[12];
    const float* b2    = (const float*)d_in[13];
    float* out = (float*)d_out;

    char* ws = (char*)d_ws;
    float*    pooled = (float*)ws;                 // 128 KB
    _Float16* emb16  = (_Float16*)(ws + 131072);   // 25.6 MB

    // 100000*128 / (256*8) = 6250 blocks exactly
    hipLaunchKernelGGL(emb_cvt_kernel, dim3(6250), dim3(256), 0, stream, emb, emb16);
    hipLaunchKernelGGL(bilstm_fused_kernel, dim3(16), dim3(512), 0, stream,
                       x, emb16, Wih_f, bih_f, bhh_f, Wih_b, bih_b, bhh_b,
                       Whh_f, Whh_b, pooled);
    hipLaunchKernelGGL(mlp_kernel, dim3(128), dim3(64), 0, stream,
                       pooled, W1, b1, W2, b2, out);
}

// Round 6
// 604.125 us; speedup vs baseline: 1.1453x; 1.1453x over previous
//
#include <hip/hip_runtime.h>
#include <hip/hip_fp16.h>

#define TT 512
#define HH 128

typedef _Float16 half2_t __attribute__((ext_vector_type(2)));
typedef _Float16 half4_t __attribute__((ext_vector_type(4)));
typedef _Float16 half8_t __attribute__((ext_vector_type(8)));
typedef float    float4_t __attribute__((ext_vector_type(4)));

__device__ __forceinline__ half2_t h2(float v) {
    half2_t r; r[0] = (_Float16)v; r[1] = (_Float16)v; return r;
}
__device__ __forceinline__ half2_t pkrtz(float a, float b) {
    return __builtin_bit_cast(half2_t, __builtin_amdgcn_cvt_pkrtz(a, b));
}

// ---- packed-f16 polynomial activations (no transcendentals) ----
#define TC1 0.994940f
#define TC3 -0.290799f
#define TC5 0.065507f
#define TC7 -0.0062464f
#define SC1 0.2487350f
#define SC3 -0.0181749f
#define SC5 0.00102355f
#define SC7 -0.0000244141f

__device__ __forceinline__ half2_t tanh_pk(half2_t x) {
    half2_t m = __builtin_elementwise_min(__builtin_elementwise_max(x, h2(-2.0f)), h2(2.0f));
    half2_t t = m * m;
    half2_t p = h2(TC7) * t + h2(TC5);
    p = p * t + h2(TC3);
    p = p * t + h2(TC1);
    return m * p;
}
__device__ __forceinline__ half2_t sigma_pk(half2_t x) {
    half2_t m = __builtin_elementwise_min(__builtin_elementwise_max(x, h2(-4.0f)), h2(4.0f));
    half2_t t = m * m;
    half2_t p = h2(SC7) * t + h2(SC5);
    p = p * t + h2(SC3);
    p = p * t + h2(SC1);
    return m * p + h2(0.5f);
}

// LDS-only barrier: waits lgkmcnt(0), leaves global loads in flight.
__device__ __forceinline__ void wg_barrier_lds() {
#if __has_builtin(__builtin_amdgcn_s_waitcnt)
    __builtin_amdgcn_s_waitcnt(0xC07F);   // lgkmcnt(0), vmcnt=max, expcnt=max
#else
    asm volatile("s_waitcnt lgkmcnt(0)" ::: "memory");
#endif
    __builtin_amdgcn_s_barrier();
}

// ---- fused BiLSTM kernel (r17).
// Fusion of xp projection into the recurrence with ALL added ops off the
// post-barrier critical path:
//  - E staged block-cooperatively: 1 float4/thread/step from f32 emb
//    (16 rows x 32 slots; ~16 TA lines/wave vs r16's 64, no 8x duplication).
//  - esm fragment-linear (r15 trick): be reads = conflict-free lane-linear
//    base,+512,+1024,+1536 like bh.
//  - 4-slot ring, 2-barrier pipeline: gather E(t+4) early step t ->
//    esm[t&3] write late step t -> be read slot (t+2)&3 late step t+1
//    (in activation shadow) -> xp-MFMA consumes at step t+2.
//  - Post-barrier LDS queue = bh only (identical to r15).
//  - gates(t) = MFMA(Whh, h(t-1), C = xp(t) f32); xp(t+1) = MFMA(Wih, E, bias).
// Deletes xp_gemm kernel + 134MB intermediate (~145us).
__global__ __attribute__((amdgpu_flat_work_group_size(512, 512), amdgpu_waves_per_eu(2, 2)))
void bilstm_fused_kernel(
    const int* __restrict__ x, const float* __restrict__ emb,
    const float* __restrict__ Wih_f, const float* __restrict__ bih_f, const float* __restrict__ bhh_f,
    const float* __restrict__ Wih_b, const float* __restrict__ bih_b, const float* __restrict__ bhh_b,
    const float* __restrict__ Whh_f, const float* __restrict__ Whh_b,
    float* __restrict__ pooled)
{
    const int wg  = blockIdx.x;        // 0..15 dirbg
    const int dir = wg >> 3, bg = wg & 7;
    const float* Wih = dir ? Wih_b : Wih_f;
    const float* bih = dir ? bih_b : bih_f;
    const float* bhh = dir ? bhh_b : bhh_f;
    const float* Whh = dir ? Whh_b : Whh_f;

    const int tid = threadIdx.x;
    const int w = tid >> 6, lane = tid & 63, lq = lane >> 4, lm = lane & 15;
    const int srow = tid >> 5, sslot = tid & 31;   // staging role

    __shared__ _Float16 hsm[2][2048];   // h tiles, fragment-linear (r15)
    __shared__ _Float16 esm[4][2048];   // E ring,  fragment-linear

    // ---- weight fragments + fused bias ----
    half8_t awih[4][4], awhh[4][4];
    #pragma unroll
    for (int T = 0; T < 4; ++T) {
        #pragma unroll
        for (int kk = 0; kk < 4; ++kk) {
            const float4* s1 = (const float4*)(Wih + (size_t)(T * 128 + w * 16 + lm) * 128 + kk * 32 + lq * 8);
            float4 v0 = s1[0], v1 = s1[1];
            half8_t h;
            half2_t a = pkrtz(v0.x, v0.y), b = pkrtz(v0.z, v0.w);
            half2_t c = pkrtz(v1.x, v1.y), d = pkrtz(v1.z, v1.w);
            h[0]=a[0]; h[1]=a[1]; h[2]=b[0]; h[3]=b[1];
            h[4]=c[0]; h[5]=c[1]; h[6]=d[0]; h[7]=d[1];
            awih[T][kk] = h;
            const float4* s2 = (const float4*)(Whh + (size_t)(T * 128 + w * 16 + lm) * 128 + kk * 32 + lq * 8);
            float4 u0 = s2[0], u1 = s2[1];
            half8_t g;
            half2_t e = pkrtz(u0.x, u0.y), f = pkrtz(u0.z, u0.w);
            half2_t gg = pkrtz(u1.x, u1.y), hh = pkrtz(u1.z, u1.w);
            g[0]=e[0]; g[1]=e[1]; g[2]=f[0]; g[3]=f[1];
            g[4]=gg[0]; g[5]=gg[1]; g[6]=hh[0]; g[7]=hh[1];
            awhh[T][kk] = g;
        }
    }
    float4_t biasv[4];
    #pragma unroll
    for (int T = 0; T < 4; ++T) {
        int g = T * 128 + w * 16 + lq * 4;
        float4 b1 = *(const float4*)(bih + g);
        float4 b2 = *(const float4*)(bhh + g);
        biasv[T] = (float4_t){b1.x + b2.x, b1.y + b2.y, b1.z + b2.z, b1.w + b2.w};
    }

    for (int k = tid; k < 2 * 2048; k += 512)
        ((_Float16*)hsm)[k] = (_Float16)0.0f;

    const int rbase = lane * 8;
    const int wbase = (w >> 1) * 512 + ((w & 1) * 2 + (lq >> 1)) * 128 + lm * 8 + (lq & 1) * 4;
    const int ebase = (sslot >> 3) * 512 + ((sslot >> 1) & 3) * 128 + srow * 8 + (sslot & 1) * 4;

    const int* xsrow = x + (size_t)(bg * 16 + srow) * TT;   // staging ids
    const int* xrow  = x + (size_t)(bg * 16 + lm) * TT;     // prologue consumer ids
    #define MPT(k_) (dir ? (TT - 1 - ((k_) < TT ? (k_) : (TT - 1))) : ((k_) < TT ? (k_) : (TT - 1)))

    // ---- prologue ----
    // stage esm[2]=E(2), esm[3]=E(3) (read at steps 0,1)
    {
        int id2 = xsrow[MPT(2)];
        int id3 = xsrow[MPT(3)];
        float4 g2 = *(const float4*)(emb + (size_t)id2 * 128 + sslot * 4);
        float4 g3 = *(const float4*)(emb + (size_t)id3 * 128 + sslot * 4);
        half2_t a2 = pkrtz(g2.x, g2.y), b2 = pkrtz(g2.z, g2.w);
        half4_t q2; q2[0]=a2[0]; q2[1]=a2[1]; q2[2]=b2[0]; q2[3]=b2[1];
        *(half4_t*)&esm[2][ebase] = q2;
        half2_t a3 = pkrtz(g3.x, g3.y), b3 = pkrtz(g3.z, g3.w);
        half4_t q3; q3[0]=a3[0]; q3[1]=a3[1]; q3[2]=b3[0]; q3[3]=b3[1];
        *(half4_t*)&esm[3][ebase] = q3;
    }
    int idA = xsrow[MPT(4)], idB;   // gather id pipeline: step0 uses id(4)

    // xp(0) and beA=E(1) via one-time direct per-lane gather (duplicated, OK once)
    float4_t xpA[4], xpB[4];
    half8_t beA[4], beB[4];
    {
        int id0 = xrow[MPT(0)];
        int id1 = xrow[MPT(1)];
        const float* e0 = emb + (size_t)id0 * 128 + lq * 8;
        const float* e1 = emb + (size_t)id1 * 128 + lq * 8;
        half8_t Et[4];
        #pragma unroll
        for (int kk = 0; kk < 4; ++kk) {
            float4 v0 = *(const float4*)(e0 + kk * 32);
            float4 v1 = *(const float4*)(e0 + kk * 32 + 4);
            half2_t a = pkrtz(v0.x, v0.y), b = pkrtz(v0.z, v0.w);
            half2_t c = pkrtz(v1.x, v1.y), d = pkrtz(v1.z, v1.w);
            half8_t h;
            h[0]=a[0]; h[1]=a[1]; h[2]=b[0]; h[3]=b[1];
            h[4]=c[0]; h[5]=c[1]; h[6]=d[0]; h[7]=d[1];
            Et[kk] = h;
            float4 u0 = *(const float4*)(e1 + kk * 32);
            float4 u1 = *(const float4*)(e1 + kk * 32 + 4);
            half2_t e = pkrtz(u0.x, u0.y), f = pkrtz(u0.z, u0.w);
            half2_t g = pkrtz(u1.x, u1.y), hh = pkrtz(u1.z, u1.w);
            half8_t h3;
            h3[0]=e[0]; h3[1]=e[1]; h3[2]=f[0]; h3[3]=f[1];
            h3[4]=g[0]; h3[5]=g[1]; h3[6]=hh[0]; h3[7]=hh[1];
            beA[kk] = h3;
        }
        #pragma unroll
        for (int T = 0; T < 4; ++T) xpA[T] = biasv[T];
        #pragma unroll
        for (int kk = 0; kk < 4; ++kk)
            #pragma unroll
            for (int T = 0; T < 4; ++T)
                xpA[T] = __builtin_amdgcn_mfma_f32_16x16x32_f16(awih[T][kk], Et[kk], xpA[T], 0, 0, 0);
    }
    __syncthreads();   // hsm zeros + esm[2]/esm[3] visible

    half2_t c01 = h2(0.0f), c23 = h2(0.0f);
    half2_t hm01 = h2(-60000.0f), hm23 = h2(-60000.0f);

    // Step t: gates(t)=Whh·h+XPIN; XPOUT=xp(t+1)=Wih·BEC+bias; gather E(t+4)
    // (IDC=id(t+4)) -> esm[SWR=t&3]; be-read slot SBE=(t+2)&3 -> BEL (shadow);
    // IDL <- id(t+5). All names static.
    #define FSTEP(T_, XPIN, XPOUT, BEC, BEL, SBE, SWR, IDC, IDL) do {                \
        const int t_ = (T_);                                                         \
        /* early: VMEM issues (consumed late this step / next step) */              \
        IDL = xsrow[MPT(t_ + 5)];                                                    \
        float4 gvS = *(const float4*)(emb + (size_t)(IDC) * 128 + sslot * 4);        \
        /* post-barrier critical path: h reads */                                    \
        const _Float16* hb = &hsm[t_ & 1][rbase];                                    \
        half8_t bh0 = *(const half8_t*)(hb);                                         \
        half8_t bh1 = *(const half8_t*)(hb + 512);                                   \
        half8_t bh2 = *(const half8_t*)(hb + 1024);                                  \
        half8_t bh3 = *(const half8_t*)(hb + 1536);                                  \
        float4_t acc[4];                                                             \
        _Pragma("unroll")                                                            \
        for (int T = 0; T < 4; ++T)                                                  \
            acc[T] = __builtin_amdgcn_mfma_f32_16x16x32_f16(awhh[T][0], bh0, XPIN[T], 0, 0, 0); \
        _Pragma("unroll")                                                            \
        for (int T = 0; T < 4; ++T)                                                  \
            acc[T] = __builtin_amdgcn_mfma_f32_16x16x32_f16(awhh[T][1], bh1, acc[T], 0, 0, 0);  \
        _Pragma("unroll")                                                            \
        for (int T = 0; T < 4; ++T)                                                  \
            acc[T] = __builtin_amdgcn_mfma_f32_16x16x32_f16(awhh[T][2], bh2, acc[T], 0, 0, 0);  \
        _Pragma("unroll")                                                            \
        for (int T = 0; T < 4; ++T)                                                  \
            acc[T] = __builtin_amdgcn_mfma_f32_16x16x32_f16(awhh[T][3], bh3, acc[T], 0, 0, 0);  \
        /* xp(t+1) from regs (fills matrix pipe) */                                  \
        _Pragma("unroll")                                                            \
        for (int T = 0; T < 4; ++T)                                                  \
            XPOUT[T] = __builtin_amdgcn_mfma_f32_16x16x32_f16(awih[T][0], BEC[0], biasv[T], 0, 0, 0); \
        _Pragma("unroll")                                                            \
        for (int kk = 1; kk < 4; ++kk)                                               \
            _Pragma("unroll")                                                        \
            for (int T = 0; T < 4; ++T)                                              \
                XPOUT[T] = __builtin_amdgcn_mfma_f32_16x16x32_f16(awih[T][kk], BEC[kk], XPOUT[T], 0, 0, 0); \
        /* be reads for step t+1 (LDS pipe, overlaps activation VALU) */             \
        const _Float16* eb = &esm[SBE][rbase];                                       \
        BEL[0] = *(const half8_t*)(eb);                                              \
        BEL[1] = *(const half8_t*)(eb + 512);                                        \
        BEL[2] = *(const half8_t*)(eb + 1024);                                       \
        BEL[3] = *(const half8_t*)(eb + 1536);                                       \
        /* activations */                                                            \
        half2_t i01 = sigma_pk(pkrtz(acc[0][0], acc[0][1]));                         \
        half2_t i23 = sigma_pk(pkrtz(acc[0][2], acc[0][3]));                         \
        half2_t f01 = sigma_pk(pkrtz(acc[1][0], acc[1][1]));                         \
        half2_t f23 = sigma_pk(pkrtz(acc[1][2], acc[1][3]));                         \
        half2_t g01 = tanh_pk(pkrtz(acc[2][0], acc[2][1]));                          \
        half2_t g23 = tanh_pk(pkrtz(acc[2][2], acc[2][3]));                          \
        half2_t o01 = sigma_pk(pkrtz(acc[3][0], acc[3][1]));                         \
        half2_t o23 = sigma_pk(pkrtz(acc[3][2], acc[3][3]));                         \
        c01 = f01 * c01 + i01 * g01;                                                 \
        c23 = f23 * c23 + i23 * g23;                                                 \
        half2_t h01 = o01 * tanh_pk(c01);                                            \
        half2_t h23 = o23 * tanh_pk(c23);                                            \
        hm01 = __builtin_elementwise_max(hm01, h01);                                 \
        hm23 = __builtin_elementwise_max(hm23, h23);                                 \
        half4_t hv4;                                                                 \
        hv4[0] = h01[0]; hv4[1] = h01[1]; hv4[2] = h23[0]; hv4[3] = h23[1];          \
        *(half4_t*)&hsm[1 - (t_ & 1)][wbase] = hv4;                                  \
        /* late: stage E(t+4) into ring slot t&3 */                                  \
        half2_t ga = pkrtz(gvS.x, gvS.y), gb = pkrtz(gvS.z, gvS.w);                  \
        half4_t gq; gq[0]=ga[0]; gq[1]=ga[1]; gq[2]=gb[0]; gq[3]=gb[1];              \
        *(half4_t*)&esm[SWR][ebase] = gq;                                            \
        wg_barrier_lds();                                                            \
    } while (0)

    #pragma unroll 1
    for (int tbs = 0; tbs < TT; tbs += 4) {
        FSTEP(tbs + 0, xpA, xpB, beA, beB, 2, 0, idA, idB);
        FSTEP(tbs + 1, xpB, xpA, beB, beA, 3, 1, idB, idA);
        FSTEP(tbs + 2, xpA, xpB, beA, beB, 0, 2, idA, idB);
        FSTEP(tbs + 3, xpB, xpA, beB, beA, 1, 3, idB, idA);
    }
    #undef FSTEP
    #undef MPT

    float4 o;
    o.x = (float)hm01[0]; o.y = (float)hm01[1];
    o.z = (float)hm23[0]; o.w = (float)hm23[1];
    *(float4*)&pooled[(size_t)(bg * 16 + lm) * 256 + dir * HH + w * 16 + lq * 4] = o;
}

// ---- kernel 3: pooled (128,256) -> relu(W1·+b1) -> sigmoid(W2·+b2) -> (128,1)
__global__ __launch_bounds__(64) void mlp_kernel(
    const float* __restrict__ pooled, const float* __restrict__ W1,
    const float* __restrict__ b1, const float* __restrict__ W2,
    const float* __restrict__ b2, float* __restrict__ out)
{
    const int b = blockIdx.x;
    const int j = threadIdx.x;
    const float4* p = (const float4*)(pooled + (size_t)b * 256);
    const float4* wv = (const float4*)(W1 + (size_t)j * 256);
    float s = 0.0f;
    #pragma unroll
    for (int q = 0; q < 64; ++q) {
        float4 pv = p[q];
        float4 ww = wv[q];
        s += pv.x * ww.x + pv.y * ww.y + pv.z * ww.z + pv.w * ww.w;
    }
    s += b1[j];
    s = fmaxf(s, 0.0f);
    float v = W2[j] * s;
    #pragma unroll
    for (int off = 32; off; off >>= 1) v += __shfl_down(v, off);
    if (j == 0) out[b] = 1.0f / (1.0f + __expf(-(v + b2[0])));
}

extern "C" void kernel_launch(void* const* d_in, const int* in_sizes, int n_in,
                              void* d_out, int out_size, void* d_ws, size_t ws_size,
                              hipStream_t stream) {
    const int*   x     = (const int*)d_in[0];
    const float* emb   = (const float*)d_in[1];
    const float* Wih_f = (const float*)d_in[2];
    const float* Whh_f = (const float*)d_in[3];
    const float* bih_f = (const float*)d_in[4];
    const float* bhh_f = (const float*)d_in[5];
    const float* Wih_b = (const float*)d_in[6];
    const float* Whh_b = (const float*)d_in[7];
    const float* bih_b = (const float*)d_in[8];
    const float* bhh_b = (const float*)d_in[9];
    const float* W1    = (const float*)d_in[10];
    const float* b1    = (const float*)d_in[11];
    const float* W2    = (const float*)d_in[12];
    const float* b2    = (const float*)d_in[13];
    float* out = (float*)d_out;

    float* pooled = (float*)d_ws;   // 128 KB

    hipLaunchKernelGGL(bilstm_fused_kernel, dim3(16), dim3(512), 0, stream,
                       x, emb, Wih_f, bih_f, bhh_f, Wih_b, bih_b, bhh_b,
                       Whh_f, Whh_b, pooled);
    hipLaunchKernelGGL(mlp_kernel, dim3(128), dim3(64), 0, stream,
                       pooled, W1, b1, W2, b2, out);
}

// Round 7
// 471.434 us; speedup vs baseline: 1.4677x; 1.2815x over previous
//
#include <hip/hip_runtime.h>
#include <hip/hip_fp16.h>

#define TT 512
#define HH 128

typedef _Float16 half2_t __attribute__((ext_vector_type(2)));
typedef _Float16 half4_t __attribute__((ext_vector_type(4)));
typedef _Float16 half8_t __attribute__((ext_vector_type(8)));
typedef float    float4_t __attribute__((ext_vector_type(4)));

__device__ __forceinline__ half2_t h2(float v) {
    half2_t r; r[0] = (_Float16)v; r[1] = (_Float16)v; return r;
}
__device__ __forceinline__ half2_t pkrtz(float a, float b) {
    return __builtin_bit_cast(half2_t, __builtin_amdgcn_cvt_pkrtz(a, b));
}

// ---- packed-f16 polynomial activations (no transcendentals) ----
#define TC1 0.994940f
#define TC3 -0.290799f
#define TC5 0.065507f
#define TC7 -0.0062464f
#define SC1 0.2487350f
#define SC3 -0.0181749f
#define SC5 0.00102355f
#define SC7 -0.0000244141f

__device__ __forceinline__ half2_t tanh_pk(half2_t x) {
    half2_t m = __builtin_elementwise_min(__builtin_elementwise_max(x, h2(-2.0f)), h2(2.0f));
    half2_t t = m * m;
    half2_t p = h2(TC7) * t + h2(TC5);
    p = p * t + h2(TC3);
    p = p * t + h2(TC1);
    return m * p;
}
__device__ __forceinline__ half2_t sigma_pk(half2_t x) {
    half2_t m = __builtin_elementwise_min(__builtin_elementwise_max(x, h2(-4.0f)), h2(4.0f));
    half2_t t = m * m;
    half2_t p = h2(SC7) * t + h2(SC5);
    p = p * t + h2(SC3);
    p = p * t + h2(SC1);
    return m * p + h2(0.5f);
}

// LDS-only barrier: waits lgkmcnt(0), leaves global loads/stores in flight.
__device__ __forceinline__ void wg_barrier_lds() {
#if __has_builtin(__builtin_amdgcn_s_waitcnt)
    __builtin_amdgcn_s_waitcnt(0xC07F);   // lgkmcnt(0), vmcnt=max, expcnt=max
#else
    asm volatile("s_waitcnt lgkmcnt(0)" ::: "memory");
#endif
    __builtin_amdgcn_s_barrier();
}

// xp layout (f16): half index = (((dirbg*512 + t)*8 + w)*64 + lane)*16,
// 16 halfs per (t,w,lane) in D-order [T*4+r]. Transposed MFMA convention:
// lane (lq,lm) holds gates T*128 + w*16 + lq*4 + r for chain bg*16+lm.
__device__ __forceinline__ size_t xp_off(int dirbg, int t, int w, int lane) {
    return (((size_t)dirbg * 512 + t) * 8 + w) * 1024 + (size_t)lane * 16;
}

// ---- kernel 1: block-staged xp GEMM.
// r18: blockIdx.y 32 -> 16. Each block does TWO 16-step halves from ONE
// weight-load+convert setup (the setup — 32 float4 L2 loads + ~150 VALU cvt
// per thread — was ~half the kernel's time at 512 blocks; 128MB of redundant
// weight re-reads drop to 64MB). 256 blocks = 1/CU, 8 waves = 2/SIMD, same
// per-CU occupancy as before.
__global__ __attribute__((amdgpu_flat_work_group_size(512, 512), amdgpu_waves_per_eu(2, 2)))
void xp_gemm_kernel(
    const int* __restrict__ x, const float* __restrict__ emb,
    const float* __restrict__ Wih_f, const float* __restrict__ bih_f, const float* __restrict__ bhh_f,
    const float* __restrict__ Wih_b, const float* __restrict__ bih_b, const float* __restrict__ bhh_b,
    _Float16* __restrict__ xp)
{
    const int wg  = blockIdx.x;        // dirbg
    const int dir = wg >> 3, bg = wg & 7;
    const int tb0 = blockIdx.y * 32;   // t-base (32 steps per block)

    const float* Wih = dir ? Wih_b : Wih_f;
    const float* bih = dir ? bih_b : bih_f;
    const float* bhh = dir ? bhh_b : bhh_f;

    const int tid = threadIdx.x;
    const int w = tid >> 6, lane = tid & 63, lq = lane >> 4, lm = lane & 15;

    __shared__ int id_sm[512];                 // [chain][t 0..31]
    __shared__ _Float16 Esm[256 * 136];        // [t*16+chain][col], +8 pad

    id_sm[tid] = x[(size_t)(bg * 16 + (tid >> 5)) * TT + tb0 + (tid & 31)];

    half8_t awih[4][4];
    #pragma unroll
    for (int T = 0; T < 4; ++T) {
        #pragma unroll
        for (int kk = 0; kk < 4; ++kk) {
            const float4* s = (const float4*)(Wih + (size_t)(T * 128 + w * 16 + lm) * 128 + kk * 32 + lq * 8);
            float4 v0 = s[0], v1 = s[1];
            half8_t h;
            half2_t a = pkrtz(v0.x, v0.y), b = pkrtz(v0.z, v0.w);
            half2_t c = pkrtz(v1.x, v1.y), d = pkrtz(v1.z, v1.w);
            h[0]=a[0]; h[1]=a[1]; h[2]=b[0]; h[3]=b[1];
            h[4]=c[0]; h[5]=c[1]; h[6]=d[0]; h[7]=d[1];
            awih[T][kk] = h;
        }
    }
    float4_t biasv[4];
    #pragma unroll
    for (int T = 0; T < 4; ++T) {
        int g = T * 128 + w * 16 + lq * 4;
        float4 b1 = *(const float4*)(bih + g);
        float4 b2 = *(const float4*)(bhh + g);
        biasv[T] = (float4_t){b1.x + b2.x, b1.y + b2.y, b1.z + b2.z, b1.w + b2.w};
    }

    #pragma unroll 1
    for (int half = 0; half < 2; ++half) {
        __syncthreads();   // id_sm ready (half 0) / Esm reads done (half 1)

        {   // stage phase: 2 threads per (chain,t) row, 16 float4 each
            const int r  = tid >> 1;
            const int hf = tid & 1;
            const int chain = r >> 4, tt2 = r & 15;
            const float* src = emb + (size_t)id_sm[chain * 32 + half * 16 + tt2] * 128 + hf * 64;
            float4 v[16];
            #pragma unroll
            for (int j = 0; j < 16; ++j) v[j] = *(const float4*)(src + 4 * j);
            _Float16* dst = &Esm[(tt2 * 16 + chain) * 136 + hf * 64];
            #pragma unroll
            for (int j = 0; j < 16; ++j) {
                half2_t a = pkrtz(v[j].x, v[j].y), b = pkrtz(v[j].z, v[j].w);
                half4_t q; q[0]=a[0]; q[1]=a[1]; q[2]=b[0]; q[3]=b[1];
                *(half4_t*)(dst + 4 * j) = q;
            }
        }
        __syncthreads();   // Esm ready; read-only in compute phase

        const int tb = tb0 + half * 16;
        #pragma unroll 4
        for (int i = 0; i < 16; ++i) {
            half8_t bfr[4];
            #pragma unroll
            for (int kk = 0; kk < 4; ++kk)
                bfr[kk] = *(const half8_t*)&Esm[(i * 16 + lm) * 136 + kk * 32 + lq * 8];

            float4_t acc[4];
            #pragma unroll
            for (int T = 0; T < 4; ++T) acc[T] = biasv[T];
            #pragma unroll
            for (int kk = 0; kk < 4; ++kk)
                #pragma unroll
                for (int T = 0; T < 4; ++T)
                    acc[T] = __builtin_amdgcn_mfma_f32_16x16x32_f16(awih[T][kk], bfr[kk], acc[T], 0, 0, 0);

            half8_t p0, p1;
            {
                half2_t a = pkrtz(acc[0][0], acc[0][1]), b = pkrtz(acc[0][2], acc[0][3]);
                half2_t c = pkrtz(acc[1][0], acc[1][1]), d = pkrtz(acc[1][2], acc[1][3]);
                p0[0]=a[0]; p0[1]=a[1]; p0[2]=b[0]; p0[3]=b[1];
                p0[4]=c[0]; p0[5]=c[1]; p0[6]=d[0]; p0[7]=d[1];
            }
            {
                half2_t a = pkrtz(acc[2][0], acc[2][1]), b = pkrtz(acc[2][2], acc[2][3]);
                half2_t c = pkrtz(acc[3][0], acc[3][1]), d = pkrtz(acc[3][2], acc[3][3]);
                p1[0]=a[0]; p1[1]=a[1]; p1[2]=b[0]; p1[3]=b[1];
                p1[4]=c[0]; p1[5]=c[1]; p1[6]=d[0]; p1[7]=d[1];
            }
            half8_t* dst = (half8_t*)(xp + xp_off(wg, tb + i, w, lane));
            dst[0] = p0; dst[1] = p1;
        }
    }
}

// ---- kernel 2: recurrence (r15 proven 319us) + running-pointer xp prefetch.
// hsm fragment-linear [buf][kk*512+lane*8+j]: bh reads are per-lane-linear
// (conflict-free); write-side permutation wbase (element-verified r15).
// r18 micro: xp prefetch walks a single pointer by +/-8192 halfs per step
// (no per-step clamp/mul); workspace padded +32KB so the 2-step lookahead
// never faults (prefetches at t=TT-2,TT-1 are never consumed).
__global__ __attribute__((amdgpu_flat_work_group_size(512, 512), amdgpu_waves_per_eu(2, 2)))
void bilstm_rec_kernel(
    const _Float16* __restrict__ xp,
    const float* __restrict__ Whh_f, const float* __restrict__ Whh_b,
    float* __restrict__ pooled)
{
    const int wg  = blockIdx.x;        // 0..15 dirbg
    const int dir = wg >> 3, bg = wg & 7;
    const float* Whh = dir ? Whh_b : Whh_f;

    const int tid = threadIdx.x;
    const int w = tid >> 6, lane = tid & 63, lq = lane >> 4, lm = lane & 15;

    __shared__ _Float16 hsm[2][2048];   // [buf][kk*512 + lane*8 + j] fragment-linear

    half8_t awhh[4][4];
    #pragma unroll
    for (int T = 0; T < 4; ++T) {
        #pragma unroll
        for (int kk = 0; kk < 4; ++kk) {
            const float4* s = (const float4*)(Whh + (size_t)(T * 128 + w * 16 + lm) * 128 + kk * 32 + lq * 8);
            float4 v0 = s[0], v1 = s[1];
            half8_t h;
            half2_t a = pkrtz(v0.x, v0.y), b = pkrtz(v0.z, v0.w);
            half2_t c = pkrtz(v1.x, v1.y), d = pkrtz(v1.z, v1.w);
            h[0]=a[0]; h[1]=a[1]; h[2]=b[0]; h[3]=b[1];
            h[4]=c[0]; h[5]=c[1]; h[6]=d[0]; h[7]=d[1];
            awhh[T][kk] = h;
        }
    }

    for (int k = tid; k < 2 * 2048; k += 512)
        ((_Float16*)hsm)[k] = (_Float16)0.0f;

    const int rbase = lane * 8;
    const int wbase = (w >> 1) * 512 + ((w & 1) * 2 + (lq >> 1)) * 128 + lm * 8 + (lq & 1) * 4;

    const _Float16* xp_wl = xp + ((size_t)wg * 512 * 8 + w) * 1024 + (size_t)lane * 16;
    const ptrdiff_t dstep = dir ? -8192 : 8192;   // halfs per logical step

    half8_t Qa[4], Qb[4];
    {
        const half8_t* p = (const half8_t*)(xp_wl + (ptrdiff_t)(dir ? (TT - 1) : 0) * 8192);
        Qa[0] = p[0]; Qb[0] = p[1];
    }
    {
        const half8_t* p = (const half8_t*)(xp_wl + (ptrdiff_t)(dir ? (TT - 2) : 1) * 8192);
        Qa[1] = p[0]; Qb[1] = p[1];
    }
    // running prefetch pointer at logical t=2
    const _Float16* xq = xp_wl + (ptrdiff_t)(dir ? (TT - 3) : 2) * 8192;
    __syncthreads();

    const float4_t zz = {0.0f, 0.0f, 0.0f, 0.0f};   // persistent zero C-input
    half2_t c01 = h2(0.0f), c23 = h2(0.0f);
    half2_t hm01 = h2(-60000.0f), hm23 = h2(-60000.0f);

    for (int tbs = 0; tbs < TT; tbs += 4) {
        #pragma unroll
        for (int P = 0; P < 4; ++P) {
            {   // prefetch xp(t+2) into buffer (P+2)&3; pointer walk, no clamp
                const half8_t* pp = (const half8_t*)xq;
                Qa[(P + 2) & 3] = pp[0]; Qb[(P + 2) & 3] = pp[1];
                xq += dstep;
            }

            const _Float16* hb = &hsm[P & 1][rbase];
            half8_t bh0 = *(const half8_t*)(hb);
            half8_t bh1 = *(const half8_t*)(hb + 512);
            half8_t bh2 = *(const half8_t*)(hb + 1024);
            half8_t bh3 = *(const half8_t*)(hb + 1536);

            float4_t acc[4];
            #pragma unroll
            for (int T = 0; T < 4; ++T)
                acc[T] = __builtin_amdgcn_mfma_f32_16x16x32_f16(awhh[T][0], bh0, zz, 0, 0, 0);
            #pragma unroll
            for (int T = 0; T < 4; ++T)
                acc[T] = __builtin_amdgcn_mfma_f32_16x16x32_f16(awhh[T][1], bh1, acc[T], 0, 0, 0);
            #pragma unroll
            for (int T = 0; T < 4; ++T)
                acc[T] = __builtin_amdgcn_mfma_f32_16x16x32_f16(awhh[T][2], bh2, acc[T], 0, 0, 0);
            #pragma unroll
            for (int T = 0; T < 4; ++T)
                acc[T] = __builtin_amdgcn_mfma_f32_16x16x32_f16(awhh[T][3], bh3, acc[T], 0, 0, 0);

            // xp half2 views (alias Q's VGPRs; no conversion instructions)
            half2_t qa0 = __builtin_shufflevector(Qa[P], Qa[P], 0, 1);
            half2_t qa1 = __builtin_shufflevector(Qa[P], Qa[P], 2, 3);
            half2_t qa2 = __builtin_shufflevector(Qa[P], Qa[P], 4, 5);
            half2_t qa3 = __builtin_shufflevector(Qa[P], Qa[P], 6, 7);
            half2_t qb0 = __builtin_shufflevector(Qb[P], Qb[P], 0, 1);
            half2_t qb1 = __builtin_shufflevector(Qb[P], Qb[P], 2, 3);
            half2_t qb2 = __builtin_shufflevector(Qb[P], Qb[P], 4, 5);
            half2_t qb3 = __builtin_shufflevector(Qb[P], Qb[P], 6, 7);

            half2_t i01 = sigma_pk(pkrtz(acc[0][0], acc[0][1]) + qa0);
            half2_t i23 = sigma_pk(pkrtz(acc[0][2], acc[0][3]) + qa1);
            half2_t f01 = sigma_pk(pkrtz(acc[1][0], acc[1][1]) + qa2);
            half2_t f23 = sigma_pk(pkrtz(acc[1][2], acc[1][3]) + qa3);
            half2_t g01 = tanh_pk(pkrtz(acc[2][0], acc[2][1]) + qb0);
            half2_t g23 = tanh_pk(pkrtz(acc[2][2], acc[2][3]) + qb1);
            half2_t o01 = sigma_pk(pkrtz(acc[3][0], acc[3][1]) + qb2);
            half2_t o23 = sigma_pk(pkrtz(acc[3][2], acc[3][3]) + qb3);

            c01 = f01 * c01 + i01 * g01;
            c23 = f23 * c23 + i23 * g23;
            half2_t h01 = o01 * tanh_pk(c01);
            half2_t h23 = o23 * tanh_pk(c23);
            hm01 = __builtin_elementwise_max(hm01, h01);
            hm23 = __builtin_elementwise_max(hm23, h23);

            half4_t hv4;
            hv4[0] = h01[0]; hv4[1] = h01[1]; hv4[2] = h23[0]; hv4[3] = h23[1];
            *(half4_t*)&hsm[1 - (P & 1)][wbase] = hv4;

            wg_barrier_lds();
        }
    }

    float4 o;
    o.x = (float)hm01[0]; o.y = (float)hm01[1];
    o.z = (float)hm23[0]; o.w = (float)hm23[1];
    *(float4*)&pooled[(size_t)(bg * 16 + lm) * 256 + dir * HH + w * 16 + lq * 4] = o;
}

// ---- kernel 3: pooled (128,256) -> relu(W1·+b1) -> sigmoid(W2·+b2) -> (128,1)
__global__ __launch_bounds__(64) void mlp_kernel(
    const float* __restrict__ pooled, const float* __restrict__ W1,
    const float* __restrict__ b1, const float* __restrict__ W2,
    const float* __restrict__ b2, float* __restrict__ out)
{
    const int b = blockIdx.x;
    const int j = threadIdx.x;
    const float4* p = (const float4*)(pooled + (size_t)b * 256);
    const float4* wv = (const float4*)(W1 + (size_t)j * 256);
    float s = 0.0f;
    #pragma unroll
    for (int q = 0; q < 64; ++q) {
        float4 pv = p[q];
        float4 ww = wv[q];
        s += pv.x * ww.x + pv.y * ww.y + pv.z * ww.z + pv.w * ww.w;
    }
    s += b1[j];
    s = fmaxf(s, 0.0f);
    float v = W2[j] * s;
    #pragma unroll
    for (int off = 32; off; off >>= 1) v += __shfl_down(v, off);
    if (j == 0) out[b] = 1.0f / (1.0f + __expf(-(v + b2[0])));
}

extern "C" void kernel_launch(void* const* d_in, const int* in_sizes, int n_in,
                              void* d_out, int out_size, void* d_ws, size_t ws_size,
                              hipStream_t stream) {
    const int*   x     = (const int*)d_in[0];
    const float* emb   = (const float*)d_in[1];
    const float* Wih_f = (const float*)d_in[2];
    const float* Whh_f = (const float*)d_in[3];
    const float* bih_f = (const float*)d_in[4];
    const float* bhh_f = (const float*)d_in[5];
    const float* Wih_b = (const float*)d_in[6];
    const float* Whh_b = (const float*)d_in[7];
    const float* bih_b = (const float*)d_in[8];
    const float* bhh_b = (const float*)d_in[9];
    const float* W1    = (const float*)d_in[10];
    const float* b1    = (const float*)d_in[11];
    const float* W2    = (const float*)d_in[12];
    const float* b2    = (const float*)d_in[13];
    float* out = (float*)d_out;

    char* ws = (char*)d_ws;
    float*    pooled = (float*)ws;                 // 128 KB
    _Float16* xp     = (_Float16*)(ws + 131072);   // 134.2 MB + 32KB pad for prefetch walk

    hipLaunchKernelGGL(xp_gemm_kernel, dim3(16, 16), dim3(512), 0, stream,
                       x, emb, Wih_f, bih_f, bhh_f, Wih_b, bih_b, bhh_b, xp);
    hipLaunchKernelGGL(bilstm_rec_kernel, dim3(16), dim3(512), 0, stream,
                       xp, Whh_f, Whh_b, pooled);
    hipLaunchKernelGGL(mlp_kernel, dim3(128), dim3(64), 0, stream,
                       pooled, W1, b1, W2, b2, out);
}

// Round 8
// 468.133 us; speedup vs baseline: 1.4781x; 1.0071x over previous
//
#include <hip/hip_runtime.h>
#include <hip/hip_fp16.h>

#define TT 512
#define HH 128

typedef _Float16 half2_t __attribute__((ext_vector_type(2)));
typedef _Float16 half4_t __attribute__((ext_vector_type(4)));
typedef _Float16 half8_t __attribute__((ext_vector_type(8)));
typedef float    float4_t __attribute__((ext_vector_type(4)));

__device__ __forceinline__ half2_t h2(float v) {
    half2_t r; r[0] = (_Float16)v; r[1] = (_Float16)v; return r;
}
__device__ __forceinline__ half2_t pkrtz(float a, float b) {
    return __builtin_bit_cast(half2_t, __builtin_amdgcn_cvt_pkrtz(a, b));
}

// ---- packed-f16 polynomial activations (no transcendentals) ----
#define TC1 0.994940f
#define TC3 -0.290799f
#define TC5 0.065507f
#define TC7 -0.0062464f
#define SC1 0.2487350f
#define SC3 -0.0181749f
#define SC5 0.00102355f
#define SC7 -0.0000244141f

__device__ __forceinline__ half2_t tanh_pk(half2_t x) {
    half2_t m = __builtin_elementwise_min(__builtin_elementwise_max(x, h2(-2.0f)), h2(2.0f));
    half2_t t = m * m;
    half2_t p = h2(TC7) * t + h2(TC5);
    p = p * t + h2(TC3);
    p = p * t + h2(TC1);
    return m * p;
}
__device__ __forceinline__ half2_t sigma_pk(half2_t x) {
    half2_t m = __builtin_elementwise_min(__builtin_elementwise_max(x, h2(-4.0f)), h2(4.0f));
    half2_t t = m * m;
    half2_t p = h2(SC7) * t + h2(SC5);
    p = p * t + h2(SC3);
    p = p * t + h2(SC1);
    return m * p + h2(0.5f);
}

// LDS-only barrier: waits lgkmcnt(0), leaves global loads/stores in flight.
__device__ __forceinline__ void wg_barrier_lds() {
#if __has_builtin(__builtin_amdgcn_s_waitcnt)
    __builtin_amdgcn_s_waitcnt(0xC07F);   // lgkmcnt(0), vmcnt=max, expcnt=max
#else
    asm volatile("s_waitcnt lgkmcnt(0)" ::: "memory");
#endif
    __builtin_amdgcn_s_barrier();
}

// xp layout (f16): half index = (((dirbg*512 + t)*8 + w)*64 + lane)*16,
// 16 halfs per (t,w,lane) in D-order [T*4+r]. Transposed MFMA convention:
// lane (lq,lm) holds gates T*128 + w*16 + lq*4 + r for chain bg*16+lm.
__device__ __forceinline__ size_t xp_off(int dirbg, int t, int w, int lane) {
    return (((size_t)dirbg * 512 + t) * 8 + w) * 1024 + (size_t)lane * 16;
}

// ---- kernel 1: block-staged xp GEMM (r18 y=16 variant; ~equal to r11). ----
__global__ __attribute__((amdgpu_flat_work_group_size(512, 512), amdgpu_waves_per_eu(2, 2)))
void xp_gemm_kernel(
    const int* __restrict__ x, const float* __restrict__ emb,
    const float* __restrict__ Wih_f, const float* __restrict__ bih_f, const float* __restrict__ bhh_f,
    const float* __restrict__ Wih_b, const float* __restrict__ bih_b, const float* __restrict__ bhh_b,
    _Float16* __restrict__ xp)
{
    const int wg  = blockIdx.x;        // dirbg
    const int dir = wg >> 3, bg = wg & 7;
    const int tb0 = blockIdx.y * 32;   // t-base (32 steps per block)

    const float* Wih = dir ? Wih_b : Wih_f;
    const float* bih = dir ? bih_b : bih_f;
    const float* bhh = dir ? bhh_b : bhh_f;

    const int tid = threadIdx.x;
    const int w = tid >> 6, lane = tid & 63, lq = lane >> 4, lm = lane & 15;

    __shared__ int id_sm[512];                 // [chain][t 0..31]
    __shared__ _Float16 Esm[256 * 136];        // [t*16+chain][col], +8 pad

    id_sm[tid] = x[(size_t)(bg * 16 + (tid >> 5)) * TT + tb0 + (tid & 31)];

    half8_t awih[4][4];
    #pragma unroll
    for (int T = 0; T < 4; ++T) {
        #pragma unroll
        for (int kk = 0; kk < 4; ++kk) {
            const float4* s = (const float4*)(Wih + (size_t)(T * 128 + w * 16 + lm) * 128 + kk * 32 + lq * 8);
            float4 v0 = s[0], v1 = s[1];
            half8_t h;
            half2_t a = pkrtz(v0.x, v0.y), b = pkrtz(v0.z, v0.w);
            half2_t c = pkrtz(v1.x, v1.y), d = pkrtz(v1.z, v1.w);
            h[0]=a[0]; h[1]=a[1]; h[2]=b[0]; h[3]=b[1];
            h[4]=c[0]; h[5]=c[1]; h[6]=d[0]; h[7]=d[1];
            awih[T][kk] = h;
        }
    }
    float4_t biasv[4];
    #pragma unroll
    for (int T = 0; T < 4; ++T) {
        int g = T * 128 + w * 16 + lq * 4;
        float4 b1 = *(const float4*)(bih + g);
        float4 b2 = *(const float4*)(bhh + g);
        biasv[T] = (float4_t){b1.x + b2.x, b1.y + b2.y, b1.z + b2.z, b1.w + b2.w};
    }

    #pragma unroll 1
    for (int half = 0; half < 2; ++half) {
        __syncthreads();   // id_sm ready (half 0) / Esm reads done (half 1)

        {   // stage phase: 2 threads per (chain,t) row, 16 float4 each
            const int r  = tid >> 1;
            const int hf = tid & 1;
            const int chain = r >> 4, tt2 = r & 15;
            const float* src = emb + (size_t)id_sm[chain * 32 + half * 16 + tt2] * 128 + hf * 64;
            float4 v[16];
            #pragma unroll
            for (int j = 0; j < 16; ++j) v[j] = *(const float4*)(src + 4 * j);
            _Float16* dst = &Esm[(tt2 * 16 + chain) * 136 + hf * 64];
            #pragma unroll
            for (int j = 0; j < 16; ++j) {
                half2_t a = pkrtz(v[j].x, v[j].y), b = pkrtz(v[j].z, v[j].w);
                half4_t q; q[0]=a[0]; q[1]=a[1]; q[2]=b[0]; q[3]=b[1];
                *(half4_t*)(dst + 4 * j) = q;
            }
        }
        __syncthreads();   // Esm ready; read-only in compute phase

        const int tb = tb0 + half * 16;
        #pragma unroll 4
        for (int i = 0; i < 16; ++i) {
            half8_t bfr[4];
            #pragma unroll
            for (int kk = 0; kk < 4; ++kk)
                bfr[kk] = *(const half8_t*)&Esm[(i * 16 + lm) * 136 + kk * 32 + lq * 8];

            float4_t acc[4];
            #pragma unroll
            for (int T = 0; T < 4; ++T) acc[T] = biasv[T];
            #pragma unroll
            for (int kk = 0; kk < 4; ++kk)
                #pragma unroll
                for (int T = 0; T < 4; ++T)
                    acc[T] = __builtin_amdgcn_mfma_f32_16x16x32_f16(awih[T][kk], bfr[kk], acc[T], 0, 0, 0);

            half8_t p0, p1;
            {
                half2_t a = pkrtz(acc[0][0], acc[0][1]), b = pkrtz(acc[0][2], acc[0][3]);
                half2_t c = pkrtz(acc[1][0], acc[1][1]), d = pkrtz(acc[1][2], acc[1][3]);
                p0[0]=a[0]; p0[1]=a[1]; p0[2]=b[0]; p0[3]=b[1];
                p0[4]=c[0]; p0[5]=c[1]; p0[6]=d[0]; p0[7]=d[1];
            }
            {
                half2_t a = pkrtz(acc[2][0], acc[2][1]), b = pkrtz(acc[2][2], acc[2][3]);
                half2_t c = pkrtz(acc[3][0], acc[3][1]), d = pkrtz(acc[3][2], acc[3][3]);
                p1[0]=a[0]; p1[1]=a[1]; p1[2]=b[0]; p1[3]=b[1];
                p1[4]=c[0]; p1[5]=c[1]; p1[6]=d[0]; p1[7]=d[1];
            }
            half8_t* dst = (half8_t*)(xp + xp_off(wg, tb + i, w, lane));
            dst[0] = p0; dst[1] = p1;
        }
    }
}

// ---- kernel 2: recurrence, r19 CHAIN-SPLIT: 32 blocks, 8 real chains each.
// The rec kernel is issue-bound (r18 ledger: VALU 868 + MFMA 512 of 1524
// cy/step/SIMD). Chains are independent; MFMA B-columns never mix. Each
// block owns 8 chains; columns 8-15 duplicate columns 0-7 (lm>=8 threads
// read the xp of chain lm-8, dynamics duplicate exactly -> bit-identical).
// Per-SIMD VALU halves; 2x CUs. Only xp lane index, grid, pooled-guard
// changed vs the proven r15 kernel. hsm fragment-linear, clamped prefetch.
__global__ __attribute__((amdgpu_flat_work_group_size(512, 512), amdgpu_waves_per_eu(2, 2)))
void bilstm_rec_kernel(
    const _Float16* __restrict__ xp,
    const float* __restrict__ Whh_f, const float* __restrict__ Whh_b,
    float* __restrict__ pooled)
{
    const int wg   = blockIdx.x;        // 0..31
    const int dir  = wg >> 4;
    const int rem  = wg & 15;
    const int bgf  = rem >> 1;          // 0..7 full batch group
    const int hsel = rem & 1;           // which 8-chain half
    const float* Whh = dir ? Whh_b : Whh_f;

    const int tid = threadIdx.x;
    const int w = tid >> 6, lane = tid & 63, lq = lane >> 4, lm = lane & 15;

    __shared__ _Float16 hsm[2][2048];   // [buf][kk*512 + lane*8 + j] fragment-linear

    half8_t awhh[4][4];
    #pragma unroll
    for (int T = 0; T < 4; ++T) {
        #pragma unroll
        for (int kk = 0; kk < 4; ++kk) {
            const float4* s = (const float4*)(Whh + (size_t)(T * 128 + w * 16 + lm) * 128 + kk * 32 + lq * 8);
            float4 v0 = s[0], v1 = s[1];
            half8_t h;
            half2_t a = pkrtz(v0.x, v0.y), b = pkrtz(v0.z, v0.w);
            half2_t c = pkrtz(v1.x, v1.y), d = pkrtz(v1.z, v1.w);
            h[0]=a[0]; h[1]=a[1]; h[2]=b[0]; h[3]=b[1];
            h[4]=c[0]; h[5]=c[1]; h[6]=d[0]; h[7]=d[1];
            awhh[T][kk] = h;
        }
    }

    for (int k = tid; k < 2 * 2048; k += 512)
        ((_Float16*)hsm)[k] = (_Float16)0.0f;

    const int rbase = lane * 8;
    const int wbase = (w >> 1) * 512 + ((w & 1) * 2 + (lq >> 1)) * 128 + lm * 8 + (lq & 1) * 4;

    // xp source: dirbg block (dir, bgf); column = hsel*8 + (lm&7)
    const int dirbg_xp = dir * 8 + bgf;
    const int lane_xp  = lq * 16 + hsel * 8 + (lm & 7);
    const _Float16* xp_wl = xp + ((size_t)dirbg_xp * 512 * 8 + w) * 1024 + (size_t)lane_xp * 16;

    half8_t Qa[4], Qb[4];
    {
        int ta = dir ? (TT - 1) : 0;
        const half8_t* p = (const half8_t*)(xp_wl + (size_t)ta * 8192);
        Qa[0] = p[0]; Qb[0] = p[1];
    }
    {
        int ta = dir ? (TT - 2) : 1;
        const half8_t* p = (const half8_t*)(xp_wl + (size_t)ta * 8192);
        Qa[1] = p[0]; Qb[1] = p[1];
    }
    __syncthreads();

    const float4_t zz = {0.0f, 0.0f, 0.0f, 0.0f};   // persistent zero C-input
    half2_t c01 = h2(0.0f), c23 = h2(0.0f);
    half2_t hm01 = h2(-60000.0f), hm23 = h2(-60000.0f);

    for (int tbs = 0; tbs < TT; tbs += 4) {
        #pragma unroll
        for (int P = 0; P < 4; ++P) {
            const int t = tbs + P;
            {   // prefetch xp(t+2) into buffer (P+2)&3 (clamped, r15-proven)
                int tl = (t + 2 < TT) ? (t + 2) : (TT - 1);
                int ta = dir ? (TT - 1 - tl) : tl;
                const half8_t* pp = (const half8_t*)(xp_wl + (size_t)ta * 8192);
                Qa[(P + 2) & 3] = pp[0]; Qb[(P + 2) & 3] = pp[1];
            }

            const _Float16* hb = &hsm[P & 1][rbase];
            half8_t bh0 = *(const half8_t*)(hb);
            half8_t bh1 = *(const half8_t*)(hb + 512);
            half8_t bh2 = *(const half8_t*)(hb + 1024);
            half8_t bh3 = *(const half8_t*)(hb + 1536);

            float4_t acc[4];
            #pragma unroll
            for (int T = 0; T < 4; ++T)
                acc[T] = __builtin_amdgcn_mfma_f32_16x16x32_f16(awhh[T][0], bh0, zz, 0, 0, 0);
            #pragma unroll
            for (int T = 0; T < 4; ++T)
                acc[T] = __builtin_amdgcn_mfma_f32_16x16x32_f16(awhh[T][1], bh1, acc[T], 0, 0, 0);
            #pragma unroll
            for (int T = 0; T < 4; ++T)
                acc[T] = __builtin_amdgcn_mfma_f32_16x16x32_f16(awhh[T][2], bh2, acc[T], 0, 0, 0);
            #pragma unroll
            for (int T = 0; T < 4; ++T)
                acc[T] = __builtin_amdgcn_mfma_f32_16x16x32_f16(awhh[T][3], bh3, acc[T], 0, 0, 0);

            // xp half2 views (alias Q's VGPRs; no conversion instructions)
            half2_t qa0 = __builtin_shufflevector(Qa[P], Qa[P], 0, 1);
            half2_t qa1 = __builtin_shufflevector(Qa[P], Qa[P], 2, 3);
            half2_t qa2 = __builtin_shufflevector(Qa[P], Qa[P], 4, 5);
            half2_t qa3 = __builtin_shufflevector(Qa[P], Qa[P], 6, 7);
            half2_t qb0 = __builtin_shufflevector(Qb[P], Qb[P], 0, 1);
            half2_t qb1 = __builtin_shufflevector(Qb[P], Qb[P], 2, 3);
            half2_t qb2 = __builtin_shufflevector(Qb[P], Qb[P], 4, 5);
            half2_t qb3 = __builtin_shufflevector(Qb[P], Qb[P], 6, 7);

            half2_t i01 = sigma_pk(pkrtz(acc[0][0], acc[0][1]) + qa0);
            half2_t i23 = sigma_pk(pkrtz(acc[0][2], acc[0][3]) + qa1);
            half2_t f01 = sigma_pk(pkrtz(acc[1][0], acc[1][1]) + qa2);
            half2_t f23 = sigma_pk(pkrtz(acc[1][2], acc[1][3]) + qa3);
            half2_t g01 = tanh_pk(pkrtz(acc[2][0], acc[2][1]) + qb0);
            half2_t g23 = tanh_pk(pkrtz(acc[2][2], acc[2][3]) + qb1);
            half2_t o01 = sigma_pk(pkrtz(acc[3][0], acc[3][1]) + qb2);
            half2_t o23 = sigma_pk(pkrtz(acc[3][2], acc[3][3]) + qb3);

            c01 = f01 * c01 + i01 * g01;
            c23 = f23 * c23 + i23 * g23;
            half2_t h01 = o01 * tanh_pk(c01);
            half2_t h23 = o23 * tanh_pk(c23);
            hm01 = __builtin_elementwise_max(hm01, h01);
            hm23 = __builtin_elementwise_max(hm23, h23);

            half4_t hv4;
            hv4[0] = h01[0]; hv4[1] = h01[1]; hv4[2] = h23[0]; hv4[3] = h23[1];
            *(half4_t*)&hsm[1 - (P & 1)][wbase] = hv4;

            wg_barrier_lds();
        }
    }

    if (lm < 8) {   // lm 8-15 are duplicate columns; only real chains write
        float4 o;
        o.x = (float)hm01[0]; o.y = (float)hm01[1];
        o.z = (float)hm23[0]; o.w = (float)hm23[1];
        *(float4*)&pooled[(size_t)(bgf * 16 + hsel * 8 + lm) * 256 + dir * HH + w * 16 + lq * 4] = o;
    }
}

// ---- kernel 3: pooled (128,256) -> relu(W1·+b1) -> sigmoid(W2·+b2) -> (128,1)
__global__ __launch_bounds__(64) void mlp_kernel(
    const float* __restrict__ pooled, const float* __restrict__ W1,
    const float* __restrict__ b1, const float* __restrict__ W2,
    const float* __restrict__ b2, float* __restrict__ out)
{
    const int b = blockIdx.x;
    const int j = threadIdx.x;
    const float4* p = (const float4*)(pooled + (size_t)b * 256);
    const float4* wv = (const float4*)(W1 + (size_t)j * 256);
    float s = 0.0f;
    #pragma unroll
    for (int q = 0; q < 64; ++q) {
        float4 pv = p[q];
        float4 ww = wv[q];
        s += pv.x * ww.x + pv.y * ww.y + pv.z * ww.z + pv.w * ww.w;
    }
    s += b1[j];
    s = fmaxf(s, 0.0f);
    float v = W2[j] * s;
    #pragma unroll
    for (int off = 32; off; off >>= 1) v += __shfl_down(v, off);
    if (j == 0) out[b] = 1.0f / (1.0f + __expf(-(v + b2[0])));
}

extern "C" void kernel_launch(void* const* d_in, const int* in_sizes, int n_in,
                              void* d_out, int out_size, void* d_ws, size_t ws_size,
                              hipStream_t stream) {
    const int*   x     = (const int*)d_in[0];
    const float* emb   = (const float*)d_in[1];
    const float* Wih_f = (const float*)d_in[2];
    const float* Whh_f = (const float*)d_in[3];
    const float* bih_f = (const float*)d_in[4];
    const float* bhh_f = (const float*)d_in[5];
    const float* Wih_b = (const float*)d_in[6];
    const float* Whh_b = (const float*)d_in[7];
    const float* bih_b = (const float*)d_in[8];
    const float* bhh_b = (const float*)d_in[9];
    const float* W1    = (const float*)d_in[10];
    const float* b1    = (const float*)d_in[11];
    const float* W2    = (const float*)d_in[12];
    const float* b2    = (const float*)d_in[13];
    float* out = (float*)d_out;

    char* ws = (char*)d_ws;
    float*    pooled = (float*)ws;                 // 128 KB
    _Float16* xp     = (_Float16*)(ws + 131072);   // 134.2 MB

    hipLaunchKernelGGL(xp_gemm_kernel, dim3(16, 16), dim3(512), 0, stream,
                       x, emb, Wih_f, bih_f, bhh_f, Wih_b, bih_b, bhh_b, xp);
    hipLaunchKernelGGL(bilstm_rec_kernel, dim3(32), dim3(512), 0, stream,
                       xp, Whh_f, Whh_b, pooled);
    hipLaunchKernelGGL(mlp_kernel, dim3(128), dim3(64), 0, stream,
                       pooled, W1, b1, W2, b2, out);
}

// Round 9
// 460.535 us; speedup vs baseline: 1.5024x; 1.0165x over previous
//
#include <hip/hip_runtime.h>
#include <hip/hip_fp16.h>

#define TT 512
#define HH 128

typedef _Float16 half2_t __attribute__((ext_vector_type(2)));
typedef _Float16 half4_t __attribute__((ext_vector_type(4)));
typedef _Float16 half8_t __attribute__((ext_vector_type(8)));
typedef float    float4_t __attribute__((ext_vector_type(4)));

__device__ __forceinline__ half2_t h2(float v) {
    half2_t r; r[0] = (_Float16)v; r[1] = (_Float16)v; return r;
}
__device__ __forceinline__ half2_t pkrtz(float a, float b) {
    return __builtin_bit_cast(half2_t, __builtin_amdgcn_cvt_pkrtz(a, b));
}

// ---- packed-f16 polynomial activations (no transcendentals) ----
#define TC1 0.994940f
#define TC3 -0.290799f
#define TC5 0.065507f
#define TC7 -0.0062464f
#define SC1 0.2487350f
#define SC3 -0.0181749f
#define SC5 0.00102355f
#define SC7 -0.0000244141f

__device__ __forceinline__ half2_t tanh_pk(half2_t x) {
    half2_t m = __builtin_elementwise_min(__builtin_elementwise_max(x, h2(-2.0f)), h2(2.0f));
    half2_t t = m * m;
    half2_t p = h2(TC7) * t + h2(TC5);
    p = p * t + h2(TC3);
    p = p * t + h2(TC1);
    return m * p;
}
__device__ __forceinline__ half2_t sigma_pk(half2_t x) {
    half2_t m = __builtin_elementwise_min(__builtin_elementwise_max(x, h2(-4.0f)), h2(4.0f));
    half2_t t = m * m;
    half2_t p = h2(SC7) * t + h2(SC5);
    p = p * t + h2(SC3);
    p = p * t + h2(SC1);
    return m * p + h2(0.5f);
}

// LDS-only barrier: waits lgkmcnt(0), leaves global loads/stores in flight.
__device__ __forceinline__ void wg_barrier_lds() {
#if __has_builtin(__builtin_amdgcn_s_waitcnt)
    __builtin_amdgcn_s_waitcnt(0xC07F);   // lgkmcnt(0), vmcnt=max, expcnt=max
#else
    asm volatile("s_waitcnt lgkmcnt(0)" ::: "memory");
#endif
    __builtin_amdgcn_s_barrier();
}

// xp layout (f16): half index = (((dirbg*512 + t)*8 + w)*64 + lane)*16,
// 16 halfs per (t,w,lane) in D-order [T*4+r]. Transposed MFMA convention:
// lane (lq,lm) holds gates T*128 + w*16 + lq*4 + r for chain bg*16+lm.
__device__ __forceinline__ size_t xp_off(int dirbg, int t, int w, int lane) {
    return (((size_t)dirbg * 512 + t) * 8 + w) * 1024 + (size_t)lane * 16;
}

// ---- kernel 1: block-staged xp GEMM (r18 y=16 variant; ~equal to r11). ----
__global__ __attribute__((amdgpu_flat_work_group_size(512, 512), amdgpu_waves_per_eu(2, 2)))
void xp_gemm_kernel(
    const int* __restrict__ x, const float* __restrict__ emb,
    const float* __restrict__ Wih_f, const float* __restrict__ bih_f, const float* __restrict__ bhh_f,
    const float* __restrict__ Wih_b, const float* __restrict__ bih_b, const float* __restrict__ bhh_b,
    _Float16* __restrict__ xp)
{
    const int wg  = blockIdx.x;        // dirbg
    const int dir = wg >> 3, bg = wg & 7;
    const int tb0 = blockIdx.y * 32;   // t-base (32 steps per block)

    const float* Wih = dir ? Wih_b : Wih_f;
    const float* bih = dir ? bih_b : bih_f;
    const float* bhh = dir ? bhh_b : bhh_f;

    const int tid = threadIdx.x;
    const int w = tid >> 6, lane = tid & 63, lq = lane >> 4, lm = lane & 15;

    __shared__ int id_sm[512];                 // [chain][t 0..31]
    __shared__ _Float16 Esm[256 * 136];        // [t*16+chain][col], +8 pad

    id_sm[tid] = x[(size_t)(bg * 16 + (tid >> 5)) * TT + tb0 + (tid & 31)];

    half8_t awih[4][4];
    #pragma unroll
    for (int T = 0; T < 4; ++T) {
        #pragma unroll
        for (int kk = 0; kk < 4; ++kk) {
            const float4* s = (const float4*)(Wih + (size_t)(T * 128 + w * 16 + lm) * 128 + kk * 32 + lq * 8);
            float4 v0 = s[0], v1 = s[1];
            half8_t h;
            half2_t a = pkrtz(v0.x, v0.y), b = pkrtz(v0.z, v0.w);
            half2_t c = pkrtz(v1.x, v1.y), d = pkrtz(v1.z, v1.w);
            h[0]=a[0]; h[1]=a[1]; h[2]=b[0]; h[3]=b[1];
            h[4]=c[0]; h[5]=c[1]; h[6]=d[0]; h[7]=d[1];
            awih[T][kk] = h;
        }
    }
    float4_t biasv[4];
    #pragma unroll
    for (int T = 0; T < 4; ++T) {
        int g = T * 128 + w * 16 + lq * 4;
        float4 b1 = *(const float4*)(bih + g);
        float4 b2 = *(const float4*)(bhh + g);
        biasv[T] = (float4_t){b1.x + b2.x, b1.y + b2.y, b1.z + b2.z, b1.w + b2.w};
    }

    #pragma unroll 1
    for (int half = 0; half < 2; ++half) {
        __syncthreads();   // id_sm ready (half 0) / Esm reads done (half 1)

        {   // stage phase: 2 threads per (chain,t) row, 16 float4 each
            const int r  = tid >> 1;
            const int hf = tid & 1;
            const int chain = r >> 4, tt2 = r & 15;
            const float* src = emb + (size_t)id_sm[chain * 32 + half * 16 + tt2] * 128 + hf * 64;
            float4 v[16];
            #pragma unroll
            for (int j = 0; j < 16; ++j) v[j] = *(const float4*)(src + 4 * j);
            _Float16* dst = &Esm[(tt2 * 16 + chain) * 136 + hf * 64];
            #pragma unroll
            for (int j = 0; j < 16; ++j) {
                half2_t a = pkrtz(v[j].x, v[j].y), b = pkrtz(v[j].z, v[j].w);
                half4_t q; q[0]=a[0]; q[1]=a[1]; q[2]=b[0]; q[3]=b[1];
                *(half4_t*)(dst + 4 * j) = q;
            }
        }
        __syncthreads();   // Esm ready; read-only in compute phase

        const int tb = tb0 + half * 16;
        #pragma unroll 4
        for (int i = 0; i < 16; ++i) {
            half8_t bfr[4];
            #pragma unroll
            for (int kk = 0; kk < 4; ++kk)
                bfr[kk] = *(const half8_t*)&Esm[(i * 16 + lm) * 136 + kk * 32 + lq * 8];

            float4_t acc[4];
            #pragma unroll
            for (int T = 0; T < 4; ++T) acc[T] = biasv[T];
            #pragma unroll
            for (int kk = 0; kk < 4; ++kk)
                #pragma unroll
                for (int T = 0; T < 4; ++T)
                    acc[T] = __builtin_amdgcn_mfma_f32_16x16x32_f16(awih[T][kk], bfr[kk], acc[T], 0, 0, 0);

            half8_t p0, p1;
            {
                half2_t a = pkrtz(acc[0][0], acc[0][1]), b = pkrtz(acc[0][2], acc[0][3]);
                half2_t c = pkrtz(acc[1][0], acc[1][1]), d = pkrtz(acc[1][2], acc[1][3]);
                p0[0]=a[0]; p0[1]=a[1]; p0[2]=b[0]; p0[3]=b[1];
                p0[4]=c[0]; p0[5]=c[1]; p0[6]=d[0]; p0[7]=d[1];
            }
            {
                half2_t a = pkrtz(acc[2][0], acc[2][1]), b = pkrtz(acc[2][2], acc[2][3]);
                half2_t c = pkrtz(acc[3][0], acc[3][1]), d = pkrtz(acc[3][2], acc[3][3]);
                p1[0]=a[0]; p1[1]=a[1]; p1[2]=b[0]; p1[3]=b[1];
                p1[4]=c[0]; p1[5]=c[1]; p1[6]=d[0]; p1[7]=d[1];
            }
            half8_t* dst = (half8_t*)(xp + xp_off(wg, tb + i, w, lane));
            dst[0] = p0; dst[1] = p1;
        }
    }
}

// ---- kernel 2: recurrence (r20). r15/r18 16-block structure (chain-split
// reverted: lanes run in lockstep, duplicated chains saved zero per-wave
// work). r20 change: SOURCE-INTERLEAVED schedule — each acc[T]'s 4-MFMA
// chain is immediately followed by its activation group, and the pattern is
// pinned with sched_group_barrier ({DS_READ 4}{MFMA 4}{MFMA 4}{VALU}{MFMA 4}
// {VALU}{MFMA 4}{VALU}): the wave issues acc0's activations while acc2/3's
// MFMAs occupy the matrix pipe -> VALU (868cy) and MFMA (620cy) per SIMD
// overlap (max) instead of phase-locked sum = the measured 1524cy step.
__global__ __attribute__((amdgpu_flat_work_group_size(512, 512), amdgpu_waves_per_eu(2, 2)))
void bilstm_rec_kernel(
    const _Float16* __restrict__ xp,
    const float* __restrict__ Whh_f, const float* __restrict__ Whh_b,
    float* __restrict__ pooled)
{
    const int wg  = blockIdx.x;        // 0..15 dirbg
    const int dir = wg >> 3, bg = wg & 7;
    const float* Whh = dir ? Whh_b : Whh_f;

    const int tid = threadIdx.x;
    const int w = tid >> 6, lane = tid & 63, lq = lane >> 4, lm = lane & 15;

    __shared__ _Float16 hsm[2][2048];   // [buf][kk*512 + lane*8 + j] fragment-linear

    half8_t awhh[4][4];
    #pragma unroll
    for (int T = 0; T < 4; ++T) {
        #pragma unroll
        for (int kk = 0; kk < 4; ++kk) {
            const float4* s = (const float4*)(Whh + (size_t)(T * 128 + w * 16 + lm) * 128 + kk * 32 + lq * 8);
            float4 v0 = s[0], v1 = s[1];
            half8_t h;
            half2_t a = pkrtz(v0.x, v0.y), b = pkrtz(v0.z, v0.w);
            half2_t c = pkrtz(v1.x, v1.y), d = pkrtz(v1.z, v1.w);
            h[0]=a[0]; h[1]=a[1]; h[2]=b[0]; h[3]=b[1];
            h[4]=c[0]; h[5]=c[1]; h[6]=d[0]; h[7]=d[1];
            awhh[T][kk] = h;
        }
    }

    for (int k = tid; k < 2 * 2048; k += 512)
        ((_Float16*)hsm)[k] = (_Float16)0.0f;

    const int rbase = lane * 8;
    const int wbase = (w >> 1) * 512 + ((w & 1) * 2 + (lq >> 1)) * 128 + lm * 8 + (lq & 1) * 4;

    const _Float16* xp_wl = xp + ((size_t)wg * 512 * 8 + w) * 1024 + (size_t)lane * 16;

    half8_t Qa[4], Qb[4];
    {
        int ta = dir ? (TT - 1) : 0;
        const half8_t* p = (const half8_t*)(xp_wl + (size_t)ta * 8192);
        Qa[0] = p[0]; Qb[0] = p[1];
    }
    {
        int ta = dir ? (TT - 2) : 1;
        const half8_t* p = (const half8_t*)(xp_wl + (size_t)ta * 8192);
        Qa[1] = p[0]; Qb[1] = p[1];
    }
    __syncthreads();

    const float4_t zz = {0.0f, 0.0f, 0.0f, 0.0f};
    half2_t c01 = h2(0.0f), c23 = h2(0.0f);
    half2_t hm01 = h2(-60000.0f), hm23 = h2(-60000.0f);

    for (int tbs = 0; tbs < TT; tbs += 4) {
        #pragma unroll
        for (int P = 0; P < 4; ++P) {
            const int t = tbs + P;
            {   // prefetch xp(t+2) into buffer (P+2)&3 (clamped, proven)
                int tl = (t + 2 < TT) ? (t + 2) : (TT - 1);
                int ta = dir ? (TT - 1 - tl) : tl;
                const half8_t* pp = (const half8_t*)(xp_wl + (size_t)ta * 8192);
                Qa[(P + 2) & 3] = pp[0]; Qb[(P + 2) & 3] = pp[1];
            }

            const _Float16* hb = &hsm[P & 1][rbase];
            half8_t bh0 = *(const half8_t*)(hb);
            half8_t bh1 = *(const half8_t*)(hb + 512);
            half8_t bh2 = *(const half8_t*)(hb + 1024);
            half8_t bh3 = *(const half8_t*)(hb + 1536);

            // ---- interleaved schedule: acc chains followed by their acts ----
            // acc0 (i gates)
            float4_t a0 = __builtin_amdgcn_mfma_f32_16x16x32_f16(awhh[0][0], bh0, zz, 0, 0, 0);
            a0 = __builtin_amdgcn_mfma_f32_16x16x32_f16(awhh[0][1], bh1, a0, 0, 0, 0);
            a0 = __builtin_amdgcn_mfma_f32_16x16x32_f16(awhh[0][2], bh2, a0, 0, 0, 0);
            a0 = __builtin_amdgcn_mfma_f32_16x16x32_f16(awhh[0][3], bh3, a0, 0, 0, 0);
            // acc1 (f gates)
            float4_t a1 = __builtin_amdgcn_mfma_f32_16x16x32_f16(awhh[1][0], bh0, zz, 0, 0, 0);
            a1 = __builtin_amdgcn_mfma_f32_16x16x32_f16(awhh[1][1], bh1, a1, 0, 0, 0);
            a1 = __builtin_amdgcn_mfma_f32_16x16x32_f16(awhh[1][2], bh2, a1, 0, 0, 0);
            a1 = __builtin_amdgcn_mfma_f32_16x16x32_f16(awhh[1][3], bh3, a1, 0, 0, 0);

            half2_t qa0 = __builtin_shufflevector(Qa[P], Qa[P], 0, 1);
            half2_t qa1 = __builtin_shufflevector(Qa[P], Qa[P], 2, 3);
            half2_t i01 = sigma_pk(pkrtz(a0[0], a0[1]) + qa0);
            half2_t i23 = sigma_pk(pkrtz(a0[2], a0[3]) + qa1);

            // acc2 (g gates)
            float4_t a2 = __builtin_amdgcn_mfma_f32_16x16x32_f16(awhh[2][0], bh0, zz, 0, 0, 0);
            a2 = __builtin_amdgcn_mfma_f32_16x16x32_f16(awhh[2][1], bh1, a2, 0, 0, 0);
            a2 = __builtin_amdgcn_mfma_f32_16x16x32_f16(awhh[2][2], bh2, a2, 0, 0, 0);
            a2 = __builtin_amdgcn_mfma_f32_16x16x32_f16(awhh[2][3], bh3, a2, 0, 0, 0);

            half2_t qa2 = __builtin_shufflevector(Qa[P], Qa[P], 4, 5);
            half2_t qa3 = __builtin_shufflevector(Qa[P], Qa[P], 6, 7);
            half2_t f01 = sigma_pk(pkrtz(a1[0], a1[1]) + qa2);
            half2_t f23 = sigma_pk(pkrtz(a1[2], a1[3]) + qa3);

            // acc3 (o gates)
            float4_t a3 = __builtin_amdgcn_mfma_f32_16x16x32_f16(awhh[3][0], bh0, zz, 0, 0, 0);
            a3 = __builtin_amdgcn_mfma_f32_16x16x32_f16(awhh[3][1], bh1, a3, 0, 0, 0);
            a3 = __builtin_amdgcn_mfma_f32_16x16x32_f16(awhh[3][2], bh2, a3, 0, 0, 0);
            a3 = __builtin_amdgcn_mfma_f32_16x16x32_f16(awhh[3][3], bh3, a3, 0, 0, 0);

            half2_t qb0 = __builtin_shufflevector(Qb[P], Qb[P], 0, 1);
            half2_t qb1 = __builtin_shufflevector(Qb[P], Qb[P], 2, 3);
            half2_t g01 = tanh_pk(pkrtz(a2[0], a2[1]) + qb0);
            half2_t g23 = tanh_pk(pkrtz(a2[2], a2[3]) + qb1);

            half2_t qb2 = __builtin_shufflevector(Qb[P], Qb[P], 4, 5);
            half2_t qb3 = __builtin_shufflevector(Qb[P], Qb[P], 6, 7);
            half2_t o01 = sigma_pk(pkrtz(a3[0], a3[1]) + qb2);
            half2_t o23 = sigma_pk(pkrtz(a3[2], a3[3]) + qb3);

            c01 = f01 * c01 + i01 * g01;
            c23 = f23 * c23 + i23 * g23;
            half2_t h01 = o01 * tanh_pk(c01);
            half2_t h23 = o23 * tanh_pk(c23);
            hm01 = __builtin_elementwise_max(hm01, h01);
            hm23 = __builtin_elementwise_max(hm23, h23);

            half4_t hv4;
            hv4[0] = h01[0]; hv4[1] = h01[1]; hv4[2] = h23[0]; hv4[3] = h23[1];
            *(half4_t*)&hsm[1 - (P & 1)][wbase] = hv4;

            // Pin the weave: ds_reads first, then MFMA clusters with VALU
            // (activation) groups between them. Masks: DS_READ=0x100,
            // MFMA=0x8, VALU=0x2 (m137-verified values).
            __builtin_amdgcn_sched_group_barrier(0x100, 4, 0);  // bh0..3
            __builtin_amdgcn_sched_group_barrier(0x008, 4, 0);  // acc0 chain
            __builtin_amdgcn_sched_group_barrier(0x008, 4, 0);  // acc1 chain
            __builtin_amdgcn_sched_group_barrier(0x002, 22, 0); // i acts
            __builtin_amdgcn_sched_group_barrier(0x008, 4, 0);  // acc2 chain
            __builtin_amdgcn_sched_group_barrier(0x002, 22, 0); // f acts
            __builtin_amdgcn_sched_group_barrier(0x008, 4, 0);  // acc3 chain
            __builtin_amdgcn_sched_group_barrier(0x002, 22, 0); // g acts
            // tail (o acts, cell, write) left free

            wg_barrier_lds();
        }
    }

    float4 o;
    o.x = (float)hm01[0]; o.y = (float)hm01[1];
    o.z = (float)hm23[0]; o.w = (float)hm23[1];
    *(float4*)&pooled[(size_t)(bg * 16 + lm) * 256 + dir * HH + w * 16 + lq * 4] = o;
}

// ---- kernel 3: pooled (128,256) -> relu(W1·+b1) -> sigmoid(W2·+b2) -> (128,1)
__global__ __launch_bounds__(64) void mlp_kernel(
    const float* __restrict__ pooled, const float* __restrict__ W1,
    const float* __restrict__ b1, const float* __restrict__ W2,
    const float* __restrict__ b2, float* __restrict__ out)
{
    const int b = blockIdx.x;
    const int j = threadIdx.x;
    const float4* p = (const float4*)(pooled + (size_t)b * 256);
    const float4* wv = (const float4*)(W1 + (size_t)j * 256);
    float s = 0.0f;
    #pragma unroll
    for (int q = 0; q < 64; ++q) {
        float4 pv = p[q];
        float4 ww = wv[q];
        s += pv.x * ww.x + pv.y * ww.y + pv.z * ww.z + pv.w * ww.w;
    }
    s += b1[j];
    s = fmaxf(s, 0.0f);
    float v = W2[j] * s;
    #pragma unroll
    for (int off = 32; off; off >>= 1) v += __shfl_down(v, off);
    if (j == 0) out[b] = 1.0f / (1.0f + __expf(-(v + b2[0])));
}

extern "C" void kernel_launch(void* const* d_in, const int* in_sizes, int n_in,
                              void* d_out, int out_size, void* d_ws, size_t ws_size,
                              hipStream_t stream) {
    const int*   x     = (const int*)d_in[0];
    const float* emb   = (const float*)d_in[1];
    const float* Wih_f = (const float*)d_in[2];
    const float* Whh_f = (const float*)d_in[3];
    const float* bih_f = (const float*)d_in[4];
    const float* bhh_f = (const float*)d_in[5];
    const float* Wih_b = (const float*)d_in[6];
    const float* Whh_b = (const float*)d_in[7];
    const float* bih_b = (const float*)d_in[8];
    const float* bhh_b = (const float*)d_in[9];
    const float* W1    = (const float*)d_in[10];
    const float* b1    = (const float*)d_in[11];
    const float* W2    = (const float*)d_in[12];
    const float* b2    = (const float*)d_in[13];
    float* out = (float*)d_out;

    char* ws = (char*)d_ws;
    float*    pooled = (float*)ws;                 // 128 KB
    _Float16* xp     = (_Float16*)(ws + 131072);   // 134.2 MB

    hipLaunchKernelGGL(xp_gemm_kernel, dim3(16, 16), dim3(512), 0, stream,
                       x, emb, Wih_f, bih_f, bhh_f, Wih_b, bih_b, bhh_b, xp);
    hipLaunchKernelGGL(bilstm_rec_kernel, dim3(16), dim3(512), 0, stream,
                       xp, Whh_f, Whh_b, pooled);
    hipLaunchKernelGGL(mlp_kernel, dim3(128), dim3(64), 0, stream,
                       pooled, W1, b1, W2, b2, out);
}

// Round 10
// 457.988 us; speedup vs baseline: 1.5108x; 1.0056x over previous
//
#include <hip/hip_runtime.h>
#include <hip/hip_fp16.h>

#define TT 512
#define HH 128

typedef _Float16 half2_t __attribute__((ext_vector_type(2)));
typedef _Float16 half4_t __attribute__((ext_vector_type(4)));
typedef _Float16 half8_t __attribute__((ext_vector_type(8)));
typedef float    float4_t __attribute__((ext_vector_type(4)));

__device__ __forceinline__ half2_t h2(float v) {
    half2_t r; r[0] = (_Float16)v; r[1] = (_Float16)v; return r;
}
__device__ __forceinline__ half2_t pkrtz(float a, float b) {
    return __builtin_bit_cast(half2_t, __builtin_amdgcn_cvt_pkrtz(a, b));
}

// ---- packed-f16 polynomial activations (no transcendentals) ----
#define TC1 0.994940f
#define TC3 -0.290799f
#define TC5 0.065507f
#define TC7 -0.0062464f
#define SC1 0.2487350f
#define SC3 -0.0181749f
#define SC5 0.00102355f
#define SC7 -0.0000244141f

__device__ __forceinline__ half2_t tanh_pk(half2_t x) {
    half2_t m = __builtin_elementwise_min(__builtin_elementwise_max(x, h2(-2.0f)), h2(2.0f));
    half2_t t = m * m;
    half2_t p = h2(TC7) * t + h2(TC5);
    p = p * t + h2(TC3);
    p = p * t + h2(TC1);
    return m * p;
}
__device__ __forceinline__ half2_t sigma_pk(half2_t x) {
    half2_t m = __builtin_elementwise_min(__builtin_elementwise_max(x, h2(-4.0f)), h2(4.0f));
    half2_t t = m * m;
    half2_t p = h2(SC7) * t + h2(SC5);
    p = p * t + h2(SC3);
    p = p * t + h2(SC1);
    return m * p + h2(0.5f);
}

// LDS-only barrier: waits lgkmcnt(0), leaves global loads/stores in flight.
__device__ __forceinline__ void wg_barrier_lds() {
#if __has_builtin(__builtin_amdgcn_s_waitcnt)
    __builtin_amdgcn_s_waitcnt(0xC07F);   // lgkmcnt(0), vmcnt=max, expcnt=max
#else
    asm volatile("s_waitcnt lgkmcnt(0)" ::: "memory");
#endif
    __builtin_amdgcn_s_barrier();
}

// xp layout (f16): half index = (((dirbg*512 + t)*8 + w)*64 + lane)*16,
// 16 halfs per (t,w,lane) in D-order [T*4+r]. Transposed MFMA convention:
// lane (lq,lm) holds gates T*128 + w*16 + lq*4 + r for chain bg*16+lm.
__device__ __forceinline__ size_t xp_off(int dirbg, int t, int w, int lane) {
    return (((size_t)dirbg * 512 + t) * 8 + w) * 1024 + (size_t)lane * 16;
}

// ---- kernel 1: xp GEMM, r21 CONFLICT-FREE LDS on both sides.
// Old layout was 8-way conflicted on compute reads ((lm+lq)*4+16kk banks)
// and 16-way on staging writes (row stride 272B: 16*68 ≡ 0 mod 32).
// New: Esm fragment-linear [tile][kk*512 + lane*8 + j] — every compute
// read AND every staging write instruction covers a contiguous 1KB across
// the wave's 64 lanes -> conflict-free by construction (r15 mechanism).
// Staging: wave wv writes (tile,kk) blocks {2wv,2wv+1}x{0..3} whole; lane
// (lq,lm) sources row id[chain=lm], cols kk*32+lq*8..+8 (2 float4, 128B
// contiguous per 4 lanes). id_sm relaid [t][chain] -> broadcast reads.
__global__ __attribute__((amdgpu_flat_work_group_size(512, 512), amdgpu_waves_per_eu(2, 2)))
void xp_gemm_kernel(
    const int* __restrict__ x, const float* __restrict__ emb,
    const float* __restrict__ Wih_f, const float* __restrict__ bih_f, const float* __restrict__ bhh_f,
    const float* __restrict__ Wih_b, const float* __restrict__ bih_b, const float* __restrict__ bhh_b,
    _Float16* __restrict__ xp)
{
    const int wg  = blockIdx.x;        // dirbg
    const int dir = wg >> 3, bg = wg & 7;
    const int tb0 = blockIdx.y * 32;   // t-base (32 steps per block)

    const float* Wih = dir ? Wih_b : Wih_f;
    const float* bih = dir ? bih_b : bih_f;
    const float* bhh = dir ? bhh_b : bhh_f;

    const int tid = threadIdx.x;
    const int w = tid >> 6, lane = tid & 63, lq = lane >> 4, lm = lane & 15;

    __shared__ int id_sm[512];            // [t_local 0..31][chain 0..15]
    __shared__ _Float16 Esm[16 * 2048];   // [tile][kk*512 + lane*8 + j] fragment-linear

    // ids: [t][chain] layout; reads below are 16-bank broadcast (conflict-free)
    id_sm[tid] = x[(size_t)(bg * 16 + (tid & 15)) * TT + tb0 + (tid >> 4)];

    half8_t awih[4][4];
    #pragma unroll
    for (int T = 0; T < 4; ++T) {
        #pragma unroll
        for (int kk = 0; kk < 4; ++kk) {
            const float4* s = (const float4*)(Wih + (size_t)(T * 128 + w * 16 + lm) * 128 + kk * 32 + lq * 8);
            float4 v0 = s[0], v1 = s[1];
            half8_t h;
            half2_t a = pkrtz(v0.x, v0.y), b = pkrtz(v0.z, v0.w);
            half2_t c = pkrtz(v1.x, v1.y), d = pkrtz(v1.z, v1.w);
            h[0]=a[0]; h[1]=a[1]; h[2]=b[0]; h[3]=b[1];
            h[4]=c[0]; h[5]=c[1]; h[6]=d[0]; h[7]=d[1];
            awih[T][kk] = h;
        }
    }
    float4_t biasv[4];
    #pragma unroll
    for (int T = 0; T < 4; ++T) {
        int g = T * 128 + w * 16 + lq * 4;
        float4 b1 = *(const float4*)(bih + g);
        float4 b2 = *(const float4*)(bhh + g);
        biasv[T] = (float4_t){b1.x + b2.x, b1.y + b2.y, b1.z + b2.z, b1.w + b2.w};
    }

    #pragma unroll 1
    for (int hlf = 0; hlf < 2; ++hlf) {
        __syncthreads();   // id_sm ready (hlf 0) / prev-half Esm reads done (hlf 1)

        {   // stage: wave wv fills (tile,kk) blocks {2wv,2wv+1} x {0..3}.
            // Each block-write = 64 lanes x b128 over a contiguous 1KB.
            #pragma unroll
            for (int m = 0; m < 8; ++m) {
                const int ti = w * 2 + (m >> 2);   // tile 0..15
                const int kk = m & 3;
                const int id = id_sm[(hlf * 16 + ti) * 16 + lm];
                const float* src = emb + (size_t)id * 128 + kk * 32 + lq * 8;
                float4 v0 = *(const float4*)(src);
                float4 v1 = *(const float4*)(src + 4);
                half2_t a = pkrtz(v0.x, v0.y), b = pkrtz(v0.z, v0.w);
                half2_t c = pkrtz(v1.x, v1.y), d = pkrtz(v1.z, v1.w);
                half8_t h8;
                h8[0]=a[0]; h8[1]=a[1]; h8[2]=b[0]; h8[3]=b[1];
                h8[4]=c[0]; h8[5]=c[1]; h8[6]=d[0]; h8[7]=d[1];
                *(half8_t*)&Esm[ti * 2048 + kk * 512 + lane * 8] = h8;
            }
        }
        __syncthreads();   // Esm ready; read-only in compute phase

        const int tb = tb0 + hlf * 16;
        #pragma unroll 4
        for (int i = 0; i < 16; ++i) {
            const _Float16* eb = &Esm[i * 2048 + lane * 8];
            half8_t bfr0 = *(const half8_t*)(eb);
            half8_t bfr1 = *(const half8_t*)(eb + 512);
            half8_t bfr2 = *(const half8_t*)(eb + 1024);
            half8_t bfr3 = *(const half8_t*)(eb + 1536);

            float4_t acc[4];
            #pragma unroll
            for (int T = 0; T < 4; ++T) acc[T] = biasv[T];
            #pragma unroll
            for (int T = 0; T < 4; ++T)
                acc[T] = __builtin_amdgcn_mfma_f32_16x16x32_f16(awih[T][0], bfr0, acc[T], 0, 0, 0);
            #pragma unroll
            for (int T = 0; T < 4; ++T)
                acc[T] = __builtin_amdgcn_mfma_f32_16x16x32_f16(awih[T][1], bfr1, acc[T], 0, 0, 0);
            #pragma unroll
            for (int T = 0; T < 4; ++T)
                acc[T] = __builtin_amdgcn_mfma_f32_16x16x32_f16(awih[T][2], bfr2, acc[T], 0, 0, 0);
            #pragma unroll
            for (int T = 0; T < 4; ++T)
                acc[T] = __builtin_amdgcn_mfma_f32_16x16x32_f16(awih[T][3], bfr3, acc[T], 0, 0, 0);

            half8_t p0, p1;
            {
                half2_t a = pkrtz(acc[0][0], acc[0][1]), b = pkrtz(acc[0][2], acc[0][3]);
                half2_t c = pkrtz(acc[1][0], acc[1][1]), d = pkrtz(acc[1][2], acc[1][3]);
                p0[0]=a[0]; p0[1]=a[1]; p0[2]=b[0]; p0[3]=b[1];
                p0[4]=c[0]; p0[5]=c[1]; p0[6]=d[0]; p0[7]=d[1];
            }
            {
                half2_t a = pkrtz(acc[2][0], acc[2][1]), b = pkrtz(acc[2][2], acc[2][3]);
                half2_t c = pkrtz(acc[3][0], acc[3][1]), d = pkrtz(acc[3][2], acc[3][3]);
                p1[0]=a[0]; p1[1]=a[1]; p1[2]=b[0]; p1[3]=b[1];
                p1[4]=c[0]; p1[5]=c[1]; p1[6]=d[0]; p1[7]=d[1];
            }
            half8_t* dst = (half8_t*)(xp + xp_off(wg, tb + i, w, lane));
            dst[0] = p0; dst[1] = p1;
        }
    }
}

// ---- kernel 2: recurrence (r20 frozen: fragment-linear hsm + interleaved
// MFMA/activation schedule pinned with sched_group_barrier; 314.5us).
__global__ __attribute__((amdgpu_flat_work_group_size(512, 512), amdgpu_waves_per_eu(2, 2)))
void bilstm_rec_kernel(
    const _Float16* __restrict__ xp,
    const float* __restrict__ Whh_f, const float* __restrict__ Whh_b,
    float* __restrict__ pooled)
{
    const int wg  = blockIdx.x;        // 0..15 dirbg
    const int dir = wg >> 3, bg = wg & 7;
    const float* Whh = dir ? Whh_b : Whh_f;

    const int tid = threadIdx.x;
    const int w = tid >> 6, lane = tid & 63, lq = lane >> 4, lm = lane & 15;

    __shared__ _Float16 hsm[2][2048];   // [buf][kk*512 + lane*8 + j] fragment-linear

    half8_t awhh[4][4];
    #pragma unroll
    for (int T = 0; T < 4; ++T) {
        #pragma unroll
        for (int kk = 0; kk < 4; ++kk) {
            const float4* s = (const float4*)(Whh + (size_t)(T * 128 + w * 16 + lm) * 128 + kk * 32 + lq * 8);
            float4 v0 = s[0], v1 = s[1];
            half8_t h;
            half2_t a = pkrtz(v0.x, v0.y), b = pkrtz(v0.z, v0.w);
            half2_t c = pkrtz(v1.x, v1.y), d = pkrtz(v1.z, v1.w);
            h[0]=a[0]; h[1]=a[1]; h[2]=b[0]; h[3]=b[1];
            h[4]=c[0]; h[5]=c[1]; h[6]=d[0]; h[7]=d[1];
            awhh[T][kk] = h;
        }
    }

    for (int k = tid; k < 2 * 2048; k += 512)
        ((_Float16*)hsm)[k] = (_Float16)0.0f;

    const int rbase = lane * 8;
    const int wbase = (w >> 1) * 512 + ((w & 1) * 2 + (lq >> 1)) * 128 + lm * 8 + (lq & 1) * 4;

    const _Float16* xp_wl = xp + ((size_t)wg * 512 * 8 + w) * 1024 + (size_t)lane * 16;

    half8_t Qa[4], Qb[4];
    {
        int ta = dir ? (TT - 1) : 0;
        const half8_t* p = (const half8_t*)(xp_wl + (size_t)ta * 8192);
        Qa[0] = p[0]; Qb[0] = p[1];
    }
    {
        int ta = dir ? (TT - 2) : 1;
        const half8_t* p = (const half8_t*)(xp_wl + (size_t)ta * 8192);
        Qa[1] = p[0]; Qb[1] = p[1];
    }
    __syncthreads();

    const float4_t zz = {0.0f, 0.0f, 0.0f, 0.0f};
    half2_t c01 = h2(0.0f), c23 = h2(0.0f);
    half2_t hm01 = h2(-60000.0f), hm23 = h2(-60000.0f);

    for (int tbs = 0; tbs < TT; tbs += 4) {
        #pragma unroll
        for (int P = 0; P < 4; ++P) {
            const int t = tbs + P;
            {   // prefetch xp(t+2) into buffer (P+2)&3 (clamped, proven)
                int tl = (t + 2 < TT) ? (t + 2) : (TT - 1);
                int ta = dir ? (TT - 1 - tl) : tl;
                const half8_t* pp = (const half8_t*)(xp_wl + (size_t)ta * 8192);
                Qa[(P + 2) & 3] = pp[0]; Qb[(P + 2) & 3] = pp[1];
            }

            const _Float16* hb = &hsm[P & 1][rbase];
            half8_t bh0 = *(const half8_t*)(hb);
            half8_t bh1 = *(const half8_t*)(hb + 512);
            half8_t bh2 = *(const half8_t*)(hb + 1024);
            half8_t bh3 = *(const half8_t*)(hb + 1536);

            // ---- interleaved schedule: acc chains followed by their acts ----
            float4_t a0 = __builtin_amdgcn_mfma_f32_16x16x32_f16(awhh[0][0], bh0, zz, 0, 0, 0);
            a0 = __builtin_amdgcn_mfma_f32_16x16x32_f16(awhh[0][1], bh1, a0, 0, 0, 0);
            a0 = __builtin_amdgcn_mfma_f32_16x16x32_f16(awhh[0][2], bh2, a0, 0, 0, 0);
            a0 = __builtin_amdgcn_mfma_f32_16x16x32_f16(awhh[0][3], bh3, a0, 0, 0, 0);
            float4_t a1 = __builtin_amdgcn_mfma_f32_16x16x32_f16(awhh[1][0], bh0, zz, 0, 0, 0);
            a1 = __builtin_amdgcn_mfma_f32_16x16x32_f16(awhh[1][1], bh1, a1, 0, 0, 0);
            a1 = __builtin_amdgcn_mfma_f32_16x16x32_f16(awhh[1][2], bh2, a1, 0, 0, 0);
            a1 = __builtin_amdgcn_mfma_f32_16x16x32_f16(awhh[1][3], bh3, a1, 0, 0, 0);

            half2_t qa0 = __builtin_shufflevector(Qa[P], Qa[P], 0, 1);
            half2_t qa1 = __builtin_shufflevector(Qa[P], Qa[P], 2, 3);
            half2_t i01 = sigma_pk(pkrtz(a0[0], a0[1]) + qa0);
            half2_t i23 = sigma_pk(pkrtz(a0[2], a0[3]) + qa1);

            float4_t a2 = __builtin_amdgcn_mfma_f32_16x16x32_f16(awhh[2][0], bh0, zz, 0, 0, 0);
            a2 = __builtin_amdgcn_mfma_f32_16x16x32_f16(awhh[2][1], bh1, a2, 0, 0, 0);
            a2 = __builtin_amdgcn_mfma_f32_16x16x32_f16(awhh[2][2], bh2, a2, 0, 0, 0);
            a2 = __builtin_amdgcn_mfma_f32_16x16x32_f16(awhh[2][3], bh3, a2, 0, 0, 0);

            half2_t qa2 = __builtin_shufflevector(Qa[P], Qa[P], 4, 5);
            half2_t qa3 = __builtin_shufflevector(Qa[P], Qa[P], 6, 7);
            half2_t f01 = sigma_pk(pkrtz(a1[0], a1[1]) + qa2);
            half2_t f23 = sigma_pk(pkrtz(a1[2], a1[3]) + qa3);

            float4_t a3 = __builtin_amdgcn_mfma_f32_16x16x32_f16(awhh[3][0], bh0, zz, 0, 0, 0);
            a3 = __builtin_amdgcn_mfma_f32_16x16x32_f16(awhh[3][1], bh1, a3, 0, 0, 0);
            a3 = __builtin_amdgcn_mfma_f32_16x16x32_f16(awhh[3][2], bh2, a3, 0, 0, 0);
            a3 = __builtin_amdgcn_mfma_f32_16x16x32_f16(awhh[3][3], bh3, a3, 0, 0, 0);

            half2_t qb0 = __builtin_shufflevector(Qb[P], Qb[P], 0, 1);
            half2_t qb1 = __builtin_shufflevector(Qb[P], Qb[P], 2, 3);
            half2_t g01 = tanh_pk(pkrtz(a2[0], a2[1]) + qb0);
            half2_t g23 = tanh_pk(pkrtz(a2[2], a2[3]) + qb1);

            half2_t qb2 = __builtin_shufflevector(Qb[P], Qb[P], 4, 5);
            half2_t qb3 = __builtin_shufflevector(Qb[P], Qb[P], 6, 7);
            half2_t o01 = sigma_pk(pkrtz(a3[0], a3[1]) + qb2);
            half2_t o23 = sigma_pk(pkrtz(a3[2], a3[3]) + qb3);

            c01 = f01 * c01 + i01 * g01;
            c23 = f23 * c23 + i23 * g23;
            half2_t h01 = o01 * tanh_pk(c01);
            half2_t h23 = o23 * tanh_pk(c23);
            hm01 = __builtin_elementwise_max(hm01, h01);
            hm23 = __builtin_elementwise_max(hm23, h23);

            half4_t hv4;
            hv4[0] = h01[0]; hv4[1] = h01[1]; hv4[2] = h23[0]; hv4[3] = h23[1];
            *(half4_t*)&hsm[1 - (P & 1)][wbase] = hv4;

            __builtin_amdgcn_sched_group_barrier(0x100, 4, 0);  // bh0..3
            __builtin_amdgcn_sched_group_barrier(0x008, 4, 0);  // acc0 chain
            __builtin_amdgcn_sched_group_barrier(0x008, 4, 0);  // acc1 chain
            __builtin_amdgcn_sched_group_barrier(0x002, 22, 0); // i acts
            __builtin_amdgcn_sched_group_barrier(0x008, 4, 0);  // acc2 chain
            __builtin_amdgcn_sched_group_barrier(0x002, 22, 0); // f acts
            __builtin_amdgcn_sched_group_barrier(0x008, 4, 0);  // acc3 chain
            __builtin_amdgcn_sched_group_barrier(0x002, 22, 0); // g acts

            wg_barrier_lds();
        }
    }

    float4 o;
    o.x = (float)hm01[0]; o.y = (float)hm01[1];
    o.z = (float)hm23[0]; o.w = (float)hm23[1];
    *(float4*)&pooled[(size_t)(bg * 16 + lm) * 256 + dir * HH + w * 16 + lq * 4] = o;
}

// ---- kernel 3: pooled (128,256) -> relu(W1·+b1) -> sigmoid(W2·+b2) -> (128,1)
__global__ __launch_bounds__(64) void mlp_kernel(
    const float* __restrict__ pooled, const float* __restrict__ W1,
    const float* __restrict__ b1, const float* __restrict__ W2,
    const float* __restrict__ b2, float* __restrict__ out)
{
    const int b = blockIdx.x;
    const int j = threadIdx.x;
    const float4* p = (const float4*)(pooled + (size_t)b * 256);
    const float4* wv = (const float4*)(W1 + (size_t)j * 256);
    float s = 0.0f;
    #pragma unroll
    for (int q = 0; q < 64; ++q) {
        float4 pv = p[q];
        float4 ww = wv[q];
        s += pv.x * ww.x + pv.y * ww.y + pv.z * ww.z + pv.w * ww.w;
    }
    s += b1[j];
    s = fmaxf(s, 0.0f);
    float v = W2[j] * s;
    #pragma unroll
    for (int off = 32; off; off >>= 1) v += __shfl_down(v, off);
    if (j == 0) out[b] = 1.0f / (1.0f + __expf(-(v + b2[0])));
}

extern "C" void kernel_launch(void* const* d_in, const int* in_sizes, int n_in,
                              void* d_out, int out_size, void* d_ws, size_t ws_size,
                              hipStream_t stream) {
    const int*   x     = (const int*)d_in[0];
    const float* emb   = (const float*)d_in[1];
    const float* Wih_f = (const float*)d_in[2];
    const float* Whh_f = (const float*)d_in[3];
    const float* bih_f = (const float*)d_in[4];
    const float* bhh_f = (const float*)d_in[5];
    const float* Wih_b = (const float*)d_in[6];
    const float* Whh_b = (const float*)d_in[7];
    const float* bih_b = (const float*)d_in[8];
    const float* bhh_b = (const float*)d_in[9];
    const float* W1    = (const float*)d_in[10];
    const float* b1    = (const float*)d_in[11];
    const float* W2    = (const float*)d_in[12];
    const float* b2    = (const float*)d_in[13];
    float* out = (float*)d_out;

    char* ws = (char*)d_ws;
    float*    pooled = (float*)ws;                 // 128 KB
    _Float16* xp     = (_Float16*)(ws + 131072);   // 134.2 MB

    hipLaunchKernelGGL(xp_gemm_kernel, dim3(16, 16), dim3(512), 0, stream,
                       x, emb, Wih_f, bih_f, bhh_f, Wih_b, bih_b, bhh_b, xp);
    hipLaunchKernelGGL(bilstm_rec_kernel, dim3(16), dim3(512), 0, stream,
                       xp, Whh_f, Whh_b, pooled);
    hipLaunchKernelGGL(mlp_kernel, dim3(128), dim3(64), 0, stream,
                       pooled, W1, b1, W2, b2, out);
}